// Round 1
// baseline (405.674 us; speedup 1.0000x reference)
//
#include <hip/hip_runtime.h>

namespace {
constexpr int C_   = 128;
constexpr int H_   = 4;
constexpr int HD_  = 32;
constexpr int NWIN_ = 1024;
constexpr int T_   = 32;   // token chunk per LDS stage
}

__device__ __forceinline__ float dot4(const float4 a, const float4 b, float acc) {
    acc = fmaf(a.x, b.x, acc);
    acc = fmaf(a.y, b.y, acc);
    acc = fmaf(a.z, b.z, acc);
    acc = fmaf(a.w, b.w, acc);
    return acc;
}

// One block per window. 256 threads = 4 waves.
// LDS: xs/ks/vs 16KB each + kv 16KB + s 0.5KB = 64.5KB -> 2 blocks/CU.
__global__ __launch_bounds__(256)
void sla_fused(const float* __restrict__ x,       // [N][128]
               const float* __restrict__ wqkv,    // [384][128] rows: q(0..127) k(128..255) v(256..383)
               const float* __restrict__ wproj,   // [128][128]
               const float* __restrict__ bproj,   // [128]
               const int*   __restrict__ offsets, // [1025]
               float*       __restrict__ out)     // [N][128]
{
    __shared__ __align__(16) float xs[T_][C_];
    __shared__ __align__(16) float ks[T_][C_];   // k in pass1, q in pass2
    __shared__ __align__(16) float vs[T_][C_];   // v in pass1, y_norm in pass2
    __shared__ __align__(16) float kvs[H_][HD_][HD_];
    __shared__ __align__(16) float ss[H_][HD_];

    const int win = blockIdx.x;
    const int tid = threadIdx.x;
    const int beg = offsets[win];
    const int cnt = offsets[win + 1] - beg;
    if (cnt <= 0) return;

    // GEMM-phase mapping: channel pair {j0, j0+64}, token group of 8
    const int j0    = tid & 63;
    const int tbase = (tid >> 6) * 8;

    // kv-accumulation mapping: (h,c) = tid>>1, d-half = (tid&1)*16
    const int hcC = tid >> 1;
    const int hC  = hcC >> 5;
    const int cC  = hcC & 31;
    const int dC  = (tid & 1) * 16;

    float kvacc[16];
#pragma unroll
    for (int i = 0; i < 16; ++i) kvacc[i] = 0.f;
    float sacc = 0.f;

    // ================= PASS 1: k,v -> kv, s =================
    for (int t0 = 0; t0 < cnt; t0 += T_) {
        const int tc = (cnt - t0 < T_) ? (cnt - t0) : T_;
        __syncthreads();
        // stage x chunk (coalesced float4)
        for (int i = tid; i < tc * (C_ / 4); i += 256) {
            const int t  = i >> 5;
            const int c4 = i & 31;
            ((float4*)&xs[t][0])[c4] =
                ((const float4*)(x + (size_t)(beg + t0 + t) * C_))[c4];
        }
        __syncthreads();

        // k,v channels {j0, j0+64} for tokens [tbase, tbase+8)
        {
            const float* wk0p = wqkv + (size_t)(C_ + j0) * C_;
            const float* wk1p = wqkv + (size_t)(C_ + j0 + 64) * C_;
            const float* wv0p = wqkv + (size_t)(2 * C_ + j0) * C_;
            const float* wv1p = wqkv + (size_t)(2 * C_ + j0 + 64) * C_;
            float ak0[8], ak1[8], av0[8], av1[8];
#pragma unroll
            for (int t = 0; t < 8; ++t) { ak0[t] = 0.f; ak1[t] = 0.f; av0[t] = 0.f; av1[t] = 0.f; }
            for (int c = 0; c < C_; c += 4) {
                const float4 wk0 = *(const float4*)(wk0p + c);
                const float4 wk1 = *(const float4*)(wk1p + c);
                const float4 wv0 = *(const float4*)(wv0p + c);
                const float4 wv1 = *(const float4*)(wv1p + c);
#pragma unroll
                for (int t = 0; t < 8; ++t) {
                    const float4 xv = *(const float4*)(&xs[tbase + t][c]);
                    ak0[t] = dot4(xv, wk0, ak0[t]);
                    ak1[t] = dot4(xv, wk1, ak1[t]);
                    av0[t] = dot4(xv, wv0, av0[t]);
                    av1[t] = dot4(xv, wv1, av1[t]);
                }
            }
#pragma unroll
            for (int t = 0; t < 8; ++t) {
                ks[tbase + t][j0]      = fmaxf(ak0[t], 0.f);
                ks[tbase + t][j0 + 64] = fmaxf(ak1[t], 0.f);
                vs[tbase + t][j0]      = av0[t];
                vs[tbase + t][j0 + 64] = av1[t];
            }
        }
        __syncthreads();

        // accumulate kv[h][c][dC..dC+15] and s[h][c] (registers, real tokens only)
        for (int t = 0; t < tc; ++t) {
            const float  kval = ks[t][hcC];
            const float4* vp  = (const float4*)(&vs[t][hC * HD_ + dC]);
            const float4 v0 = vp[0];
            const float4 v1 = vp[1];
            const float4 v2 = vp[2];
            const float4 v3 = vp[3];
            kvacc[0]  = fmaf(kval, v0.x, kvacc[0]);
            kvacc[1]  = fmaf(kval, v0.y, kvacc[1]);
            kvacc[2]  = fmaf(kval, v0.z, kvacc[2]);
            kvacc[3]  = fmaf(kval, v0.w, kvacc[3]);
            kvacc[4]  = fmaf(kval, v1.x, kvacc[4]);
            kvacc[5]  = fmaf(kval, v1.y, kvacc[5]);
            kvacc[6]  = fmaf(kval, v1.z, kvacc[6]);
            kvacc[7]  = fmaf(kval, v1.w, kvacc[7]);
            kvacc[8]  = fmaf(kval, v2.x, kvacc[8]);
            kvacc[9]  = fmaf(kval, v2.y, kvacc[9]);
            kvacc[10] = fmaf(kval, v2.z, kvacc[10]);
            kvacc[11] = fmaf(kval, v2.w, kvacc[11]);
            kvacc[12] = fmaf(kval, v3.x, kvacc[12]);
            kvacc[13] = fmaf(kval, v3.y, kvacc[13]);
            kvacc[14] = fmaf(kval, v3.z, kvacc[14]);
            kvacc[15] = fmaf(kval, v3.w, kvacc[15]);
            sacc += kval;
        }
    }

    // publish kv, s to LDS
#pragma unroll
    for (int i = 0; i < 16; ++i) kvs[hC][cC][dC + i] = kvacc[i];
    if ((tid & 1) == 0) ss[hC][cC] = sacc;
    __syncthreads();

    // per-thread columns for phase E: thread -> (h, d), 16 tokens
    const int jE = tid & 127;
    const int hE = jE >> 5;
    const int dE = jE & 31;
    const int tE = (tid >> 7) * 16;
    float kvcol[32], sreg[32];
#pragma unroll
    for (int c = 0; c < HD_; ++c) {
        kvcol[c] = kvs[hE][c][dE];
        sreg[c]  = ss[hE][c];
    }

    // ================= PASS 2: q -> y/z -> proj =================
    for (int t0 = 0; t0 < cnt; t0 += T_) {
        const int tc = (cnt - t0 < T_) ? (cnt - t0) : T_;
        __syncthreads();
        for (int i = tid; i < tc * (C_ / 4); i += 256) {
            const int t  = i >> 5;
            const int c4 = i & 31;
            ((float4*)&xs[t][0])[c4] =
                ((const float4*)(x + (size_t)(beg + t0 + t) * C_))[c4];
        }
        __syncthreads();

        // q channels {j0, j0+64} for tokens [tbase, tbase+8) -> ks
        {
            const float* wq0p = wqkv + (size_t)j0 * C_;
            const float* wq1p = wqkv + (size_t)(j0 + 64) * C_;
            float aq0[8], aq1[8];
#pragma unroll
            for (int t = 0; t < 8; ++t) { aq0[t] = 0.f; aq1[t] = 0.f; }
            for (int c = 0; c < C_; c += 4) {
                const float4 wq0 = *(const float4*)(wq0p + c);
                const float4 wq1 = *(const float4*)(wq1p + c);
#pragma unroll
                for (int t = 0; t < 8; ++t) {
                    const float4 xv = *(const float4*)(&xs[tbase + t][c]);
                    aq0[t] = dot4(xv, wq0, aq0[t]);
                    aq1[t] = dot4(xv, wq1, aq1[t]);
                }
            }
#pragma unroll
            for (int t = 0; t < 8; ++t) {
                ks[tbase + t][j0]      = fmaxf(aq0[t], 0.f);
                ks[tbase + t][j0 + 64] = fmaxf(aq1[t], 0.f);
            }
        }
        __syncthreads();

        // y[n,h,d] = sum_c q[c]*kv[h][c][d]; z = sum_c q[c]*s[h][c]; vs = y/(z+1e-6)
        for (int tt = 0; tt < 16; ++tt) {
            const int t = tE + tt;
            const float4* qp = (const float4*)(&ks[t][hE * HD_]);
            float y = 0.f, z = 0.f;
#pragma unroll
            for (int c4 = 0; c4 < 8; ++c4) {
                const float4 q = qp[c4];
                y = fmaf(q.x, kvcol[c4 * 4 + 0], y);
                y = fmaf(q.y, kvcol[c4 * 4 + 1], y);
                y = fmaf(q.z, kvcol[c4 * 4 + 2], y);
                y = fmaf(q.w, kvcol[c4 * 4 + 3], y);
                z = fmaf(q.x, sreg[c4 * 4 + 0], z);
                z = fmaf(q.y, sreg[c4 * 4 + 1], z);
                z = fmaf(q.z, sreg[c4 * 4 + 2], z);
                z = fmaf(q.w, sreg[c4 * 4 + 3], z);
            }
            vs[t][jE] = y / (z + 1e-6f);
        }
        __syncthreads();

        // proj: out[n][{j0,j0+64}] = y_norm . wproj_row + b
        {
            const float* wp0 = wproj + (size_t)j0 * C_;
            const float* wp1 = wproj + (size_t)(j0 + 64) * C_;
            float a0[8], a1[8];
#pragma unroll
            for (int t = 0; t < 8; ++t) { a0[t] = 0.f; a1[t] = 0.f; }
            for (int c = 0; c < C_; c += 4) {
                const float4 w0 = *(const float4*)(wp0 + c);
                const float4 w1 = *(const float4*)(wp1 + c);
#pragma unroll
                for (int t = 0; t < 8; ++t) {
                    const float4 yv = *(const float4*)(&vs[tbase + t][c]);
                    a0[t] = dot4(yv, w0, a0[t]);
                    a1[t] = dot4(yv, w1, a1[t]);
                }
            }
            const float b0 = bproj[j0];
            const float b1 = bproj[j0 + 64];
#pragma unroll
            for (int t = 0; t < 8; ++t) {
                const int tt = tbase + t;
                if (tt < tc) {
                    float* orow = out + (size_t)(beg + t0 + tt) * C_;
                    orow[j0]      = a0[t] + b0;
                    orow[j0 + 64] = a1[t] + b1;
                }
            }
        }
    }
}

extern "C" void kernel_launch(void* const* d_in, const int* in_sizes, int n_in,
                              void* d_out, int out_size, void* d_ws, size_t ws_size,
                              hipStream_t stream)
{
    const float* x      = (const float*)d_in[0];
    const float* wqkv   = (const float*)d_in[1];
    const float* wproj  = (const float*)d_in[2];
    const float* bproj  = (const float*)d_in[3];
    const int*   offsets = (const int*)d_in[5];
    float* out = (float*)d_out;

    hipLaunchKernelGGL(sla_fused, dim3(NWIN_), dim3(256), 0, stream,
                       x, wqkv, wproj, bproj, offsets, out);
}

// Round 2
// 399.928 us; speedup vs baseline: 1.0144x; 1.0144x over previous
//
#include <hip/hip_runtime.h>

namespace {
constexpr int C_    = 128;
constexpr int H_    = 4;
constexpr int HD_   = 32;
constexpr int NWIN_ = 1024;
constexpr int T_    = 32;   // token chunk per LDS stage
constexpr int BLK_  = 512;  // 8 waves
}

__device__ __forceinline__ float dot4(const float4 a, const float4 b, float acc) {
    acc = fmaf(a.x, b.x, acc);
    acc = fmaf(a.y, b.y, acc);
    acc = fmaf(a.z, b.z, acc);
    acc = fmaf(a.w, b.w, acc);
    return acc;
}

// One block per window. 512 threads = 8 waves. LDS 66KB -> 2 blocks/CU -> 16 waves/CU.
__global__ __launch_bounds__(BLK_)
void sla_fused(const float* __restrict__ x,       // [N][128]
               const float* __restrict__ wqkv,    // [384][128] rows: q(0..127) k(128..255) v(256..383)
               const float* __restrict__ wproj,   // [128][128]
               const float* __restrict__ bproj,   // [128]
               const int*   __restrict__ offsets, // [1025]
               float*       __restrict__ out)     // [N][128]
{
    __shared__ __align__(16) float xs[T_][C_];
    __shared__ __align__(16) float ks[T_][C_];   // k in pass1, q in pass2
    __shared__ __align__(16) float vs[T_][C_];   // v in pass1, y_norm in pass2
    __shared__ __align__(16) float kvs[H_][HD_][HD_];
    __shared__ __align__(16) float ss[H_][HD_];

    const int win = blockIdx.x;
    const int tid = threadIdx.x;
    const int beg = offsets[win];
    const int cnt = offsets[win + 1] - beg;
    if (cnt <= 0) return;

    // GEMM-phase mapping: one channel j, token group of 8
    const int j     = tid & 127;
    const int tbase = (tid >> 7) * 8;

    // kv-accumulation mapping: (h,c) = tid>>2, d-quarter = (tid&3)*8
    const int hcC = tid >> 2;
    const int hC  = hcC >> 5;
    const int cC  = hcC & 31;
    const int dC  = (tid & 3) * 8;

    float kvacc[8];
#pragma unroll
    for (int i = 0; i < 8; ++i) kvacc[i] = 0.f;
    float sacc = 0.f;

    // ================= PASS 1: k,v -> kv, s =================
    for (int t0 = 0; t0 < cnt; t0 += T_) {
        const int tc = (cnt - t0 < T_) ? (cnt - t0) : T_;
        __syncthreads();
        // stage x chunk (coalesced float4)
        for (int i = tid; i < tc * (C_ / 4); i += BLK_) {
            const int t  = i >> 5;
            const int c4 = i & 31;
            ((float4*)&xs[t][0])[c4] =
                ((const float4*)(x + (size_t)(beg + t0 + t) * C_))[c4];
        }
        __syncthreads();

        // k,v channel j for tokens [tbase, tbase+8)
        {
            const float* wkp = wqkv + (size_t)(C_ + j) * C_;
            const float* wvp = wqkv + (size_t)(2 * C_ + j) * C_;
            float ak[8], av[8];
#pragma unroll
            for (int t = 0; t < 8; ++t) { ak[t] = 0.f; av[t] = 0.f; }
            for (int c = 0; c < C_; c += 4) {
                const float4 wk = *(const float4*)(wkp + c);
                const float4 wv = *(const float4*)(wvp + c);
#pragma unroll
                for (int t = 0; t < 8; ++t) {
                    const float4 xv = *(const float4*)(&xs[tbase + t][c]);
                    ak[t] = dot4(xv, wk, ak[t]);
                    av[t] = dot4(xv, wv, av[t]);
                }
            }
#pragma unroll
            for (int t = 0; t < 8; ++t) {
                ks[tbase + t][j] = fmaxf(ak[t], 0.f);
                vs[tbase + t][j] = av[t];
            }
        }
        __syncthreads();

        // accumulate kv[h][c][dC..dC+7] and s[h][c] (registers, real tokens only)
        for (int t = 0; t < tc; ++t) {
            const float  kval = ks[t][hcC];
            const float4* vp  = (const float4*)(&vs[t][hC * HD_ + dC]);
            const float4 v0 = vp[0];
            const float4 v1 = vp[1];
            kvacc[0] = fmaf(kval, v0.x, kvacc[0]);
            kvacc[1] = fmaf(kval, v0.y, kvacc[1]);
            kvacc[2] = fmaf(kval, v0.z, kvacc[2]);
            kvacc[3] = fmaf(kval, v0.w, kvacc[3]);
            kvacc[4] = fmaf(kval, v1.x, kvacc[4]);
            kvacc[5] = fmaf(kval, v1.y, kvacc[5]);
            kvacc[6] = fmaf(kval, v1.z, kvacc[6]);
            kvacc[7] = fmaf(kval, v1.w, kvacc[7]);
            sacc += kval;
        }
    }

    // publish kv, s to LDS
#pragma unroll
    for (int i = 0; i < 8; ++i) kvs[hC][cC][dC + i] = kvacc[i];
    if ((tid & 3) == 0) ss[hC][cC] = sacc;
    __syncthreads();

    // per-thread columns for phase E: thread -> (h, d), 8 tokens
    const int hE = j >> 5;
    const int dE = j & 31;
    float kvcol[32], sreg[32];
#pragma unroll
    for (int c = 0; c < HD_; ++c) {
        kvcol[c] = kvs[hE][c][dE];
        sreg[c]  = ss[hE][c];
    }

    // ================= PASS 2: q -> y/z -> proj =================
    for (int t0 = 0; t0 < cnt; t0 += T_) {
        const int tc = (cnt - t0 < T_) ? (cnt - t0) : T_;
        __syncthreads();
        for (int i = tid; i < tc * (C_ / 4); i += BLK_) {
            const int t  = i >> 5;
            const int c4 = i & 31;
            ((float4*)&xs[t][0])[c4] =
                ((const float4*)(x + (size_t)(beg + t0 + t) * C_))[c4];
        }
        __syncthreads();

        // q channel j for tokens [tbase, tbase+8) -> ks
        {
            const float* wqp = wqkv + (size_t)j * C_;
            float aq[8];
#pragma unroll
            for (int t = 0; t < 8; ++t) aq[t] = 0.f;
            for (int c = 0; c < C_; c += 4) {
                const float4 wq = *(const float4*)(wqp + c);
#pragma unroll
                for (int t = 0; t < 8; ++t) {
                    const float4 xv = *(const float4*)(&xs[tbase + t][c]);
                    aq[t] = dot4(xv, wq, aq[t]);
                }
            }
#pragma unroll
            for (int t = 0; t < 8; ++t)
                ks[tbase + t][j] = fmaxf(aq[t], 0.f);
        }
        __syncthreads();

        // y[n,h,d] = sum_c q[c]*kv[h][c][d]; z = sum_c q[c]*s[h][c]; vs = y/(z+1e-6)
        for (int tt = 0; tt < 8; ++tt) {
            const int t = tbase + tt;
            const float4* qp = (const float4*)(&ks[t][hE * HD_]);
            float y = 0.f, z = 0.f;
#pragma unroll
            for (int c4 = 0; c4 < 8; ++c4) {
                const float4 q = qp[c4];
                y = fmaf(q.x, kvcol[c4 * 4 + 0], y);
                y = fmaf(q.y, kvcol[c4 * 4 + 1], y);
                y = fmaf(q.z, kvcol[c4 * 4 + 2], y);
                y = fmaf(q.w, kvcol[c4 * 4 + 3], y);
                z = fmaf(q.x, sreg[c4 * 4 + 0], z);
                z = fmaf(q.y, sreg[c4 * 4 + 1], z);
                z = fmaf(q.z, sreg[c4 * 4 + 2], z);
                z = fmaf(q.w, sreg[c4 * 4 + 3], z);
            }
            vs[t][j] = y / (z + 1e-6f);
        }
        __syncthreads();

        // proj: out[n][j] = y_norm . wproj_row[j] + b[j]
        {
            const float* wp = wproj + (size_t)j * C_;
            float a[8];
#pragma unroll
            for (int t = 0; t < 8; ++t) a[t] = 0.f;
            for (int c = 0; c < C_; c += 4) {
                const float4 w = *(const float4*)(wp + c);
#pragma unroll
                for (int t = 0; t < 8; ++t) {
                    const float4 yv = *(const float4*)(&vs[tbase + t][c]);
                    a[t] = dot4(yv, w, a[t]);
                }
            }
            const float b = bproj[j];
#pragma unroll
            for (int t = 0; t < 8; ++t) {
                const int tt = tbase + t;
                if (tt < tc)
                    out[(size_t)(beg + t0 + tt) * C_ + j] = a[t] + b;
            }
        }
    }
}

extern "C" void kernel_launch(void* const* d_in, const int* in_sizes, int n_in,
                              void* d_out, int out_size, void* d_ws, size_t ws_size,
                              hipStream_t stream)
{
    const float* x       = (const float*)d_in[0];
    const float* wqkv    = (const float*)d_in[1];
    const float* wproj   = (const float*)d_in[2];
    const float* bproj   = (const float*)d_in[3];
    const int*   offsets = (const int*)d_in[5];
    float* out = (float*)d_out;

    hipLaunchKernelGGL(sla_fused, dim3(NWIN_), dim3(BLK_), 0, stream,
                       x, wqkv, wproj, bproj, offsets, out);
}

// Round 3
// 163.582 us; speedup vs baseline: 2.4799x; 2.4448x over previous
//
#include <hip/hip_runtime.h>

namespace {
constexpr int C    = 128;
constexpr int H    = 4;
constexpr int HD   = 32;
constexpr int NWIN = 1024;
constexpr int T    = 64;    // token chunk
constexpr int BLK  = 512;   // 8 waves
}

typedef __attribute__((ext_vector_type(8))) short bf16x8;
typedef __attribute__((ext_vector_type(4))) float f32x4;

__device__ __forceinline__ int imin(int a, int b) { return a < b ? a : b; }

// Split 8 fp32 into hi/lo bf16 fragments (hi = trunc, lo = trunc of residual).
// Error ~2^-16 relative; lo*lo term dropped at use site.
__device__ __forceinline__ void split8(float4 a, float4 b, bf16x8& hi, bf16x8& lo) {
    float f[8] = {a.x, a.y, a.z, a.w, b.x, b.y, b.z, b.w};
#pragma unroll
    for (int i = 0; i < 8; ++i) {
        unsigned u = __float_as_uint(f[i]);
        hi[i] = (short)(u >> 16);
        float r = f[i] - __uint_as_float(u & 0xFFFF0000u);
        lo[i] = (short)(__float_as_uint(r) >> 16);
    }
}

// One block per window, 512 threads = 8 waves. LDS ~146KB -> 1 block/CU.
__global__ __launch_bounds__(BLK)
void sla_mfma(const float* __restrict__ x,       // [N][128]
              const float* __restrict__ wqkv,    // [384][128]: q 0..127, k 128..255, v 256..383
              const float* __restrict__ wproj,   // [128][128]
              const float* __restrict__ bproj,   // [128]
              const int*   __restrict__ offsets, // [1025]
              float*       __restrict__ out)     // [N][128]
{
    // xs: x chunk, XOR-swizzled (dword index ^ ((row&7)<<2)) for conflict-free A-frag b128 reads
    __shared__ __align__(16) float xs[T * C];
    __shared__ __align__(16) float ks[T][C];       // k (relu), plain layout
    __shared__ __align__(16) float vs[T * C];      // v plain in pass1; Y swizzled in pass2
    __shared__ __align__(16) float qs[T][C];       // q (relu), plain
    __shared__ __align__(16) float kvs[H][HD][HD + 1];
    __shared__ __align__(16) float ss[H][HD];
    __shared__ __align__(16) float zs[T][H];       // 1/(z+eps)

    const int win = blockIdx.x;
    const int tid = threadIdx.x;
    const int beg = offsets[win];
    const int cnt = offsets[win + 1] - beg;
    if (cnt <= 0) return;
    const int nch = (cnt + T - 1) / T;

    const int wv = tid >> 6;   // wave 0..7
    const int ln = tid & 63;
    const int fr = ln & 15;    // A row / B col / D col within tile
    const int fg = ln >> 4;    // k-group; D row group

    // phase-B (kv accumulate) mapping: (h,c) = tid>>2, d-quarter = tid&3
    const int hc  = tid >> 2;
    const int hB  = hc >> 5;
    const int cB  = hc & 31;
    const int dqB = tid & 3;
    float kvacc[8] = {0.f, 0.f, 0.f, 0.f, 0.f, 0.f, 0.f, 0.f};
    float sacc = 0.f;

    // ---- helpers ----
    auto load_afrag = [&](const float* base, int row, int ksi, bf16x8& hi, bf16x8& lo) {
        const int kb = ksi * 32 + fg * 8;
        const int sw = (row & 7) << 2;
        float4 p0 = *(const float4*)(base + row * C + (kb ^ sw));
        float4 p1 = *(const float4*)(base + row * C + ((kb + 4) ^ sw));
        split8(p0, p1, hi, lo);
    };
    auto load_bfrag = [&](const float* wbase, int nrow, int ksi, bf16x8& hi, bf16x8& lo) {
        const float* p = wbase + (size_t)nrow * C + ksi * 32 + fg * 8;
        split8(*(const float4*)p, *(const float4*)(p + 4), hi, lo);
    };

#define STAGE(t0, tc)                                                                   \
    for (int i = tid; i < T * (C / 4); i += BLK) {                                      \
        int t = i >> 5, c4 = i & 31;                                                    \
        float4 val;                                                                     \
        if (t < (tc)) val = ((const float4*)(x + (size_t)(beg + (t0) + t) * C))[c4];    \
        else          val = float4{0.f, 0.f, 0.f, 0.f};                                 \
        int dw = (c4 * 4) ^ ((t & 7) << 2);                                             \
        *(float4*)(&xs[t * C + dw]) = val;                                              \
    }

    // ================= PASS 1: k,v GEMM (MFMA) -> kv,s accumulate (VALU) =============
    for (int c0 = 0; c0 < nch; ++c0) {
        const int t0 = c0 * T;
        const int tc = imin(T, cnt - t0);
        __syncthreads();                    // protect xs/ks/vs from previous iteration
        STAGE(t0, tc);
        __syncthreads();

        {   // k/v GEMM: wave wv owns ntiles {2wv, 2wv+1} of the 16 k/v ntiles, all 4 mtiles
            f32x4 acc[2][4];
#pragma unroll
            for (int nt = 0; nt < 2; ++nt)
#pragma unroll
                for (int m = 0; m < 4; ++m) acc[nt][m] = f32x4{0.f, 0.f, 0.f, 0.f};
            for (int ksi = 0; ksi < 4; ++ksi) {
                bf16x8 ahi[4], alo[4];
#pragma unroll
                for (int m = 0; m < 4; ++m)
                    load_afrag(xs, m * 16 + fr, ksi, ahi[m], alo[m]);
#pragma unroll
                for (int nt = 0; nt < 2; ++nt) {
                    bf16x8 bhi, blo;
                    load_bfrag(wqkv, 128 + (wv * 2 + nt) * 16 + fr, ksi, bhi, blo);
#pragma unroll
                    for (int m = 0; m < 4; ++m) {
                        acc[nt][m] = __builtin_amdgcn_mfma_f32_16x16x32_bf16(ahi[m], bhi, acc[nt][m], 0, 0, 0);
                        acc[nt][m] = __builtin_amdgcn_mfma_f32_16x16x32_bf16(ahi[m], blo, acc[nt][m], 0, 0, 0);
                        acc[nt][m] = __builtin_amdgcn_mfma_f32_16x16x32_bf16(alo[m], bhi, acc[nt][m], 0, 0, 0);
                    }
                }
            }
            // D layout: row = fg*4+e, col = fr (m89-verified)
#pragma unroll
            for (int nt = 0; nt < 2; ++nt) {
                const int ch = (wv * 2 + nt) * 16 + fr;   // 0..255: k then v
#pragma unroll
                for (int m = 0; m < 4; ++m)
#pragma unroll
                    for (int e = 0; e < 4; ++e) {
                        const int t = m * 16 + fg * 4 + e;
                        const float val = acc[nt][m][e];
                        if (ch < 128) ks[t][ch] = fmaxf(val, 0.f);
                        else          vs[t * C + (ch - 128)] = val;
                    }
            }
        }
        __syncthreads();

        {   // phase B: kv[h][c][dq*8..+8] += k[t][h,c] * v[t][h,dq*8..+8]; s += k
            const int vbase = hB * 32 + dqB * 8;
            for (int t = 0; t < T; ++t) {   // pad rows are zero -> safe
                const float kval = ks[t][hc];
                const float4 v0 = *(const float4*)(&vs[t * C + vbase]);
                const float4 v1 = *(const float4*)(&vs[t * C + vbase + 4]);
                kvacc[0] = fmaf(kval, v0.x, kvacc[0]);
                kvacc[1] = fmaf(kval, v0.y, kvacc[1]);
                kvacc[2] = fmaf(kval, v0.z, kvacc[2]);
                kvacc[3] = fmaf(kval, v0.w, kvacc[3]);
                kvacc[4] = fmaf(kval, v1.x, kvacc[4]);
                kvacc[5] = fmaf(kval, v1.y, kvacc[5]);
                kvacc[6] = fmaf(kval, v1.z, kvacc[6]);
                kvacc[7] = fmaf(kval, v1.w, kvacc[7]);
                sacc += kval;
            }
        }
    }

    // publish kv, s
#pragma unroll
    for (int i = 0; i < 8; ++i) kvs[hB][cB][dqB * 8 + i] = kvacc[i];
    if (dqB == 0) ss[hB][cB] = sacc;
    __syncthreads();

    // ================= PASS 2: q GEMM -> y/z -> proj GEMM =================
    for (int c0 = 0; c0 < nch; ++c0) {
        const int t0 = c0 * T;
        const int tc = imin(T, cnt - t0);
        if (nch > 1) {
            __syncthreads();
            STAGE(t0, tc);
            __syncthreads();
        }

        {   // q GEMM: wave wv -> ntile wv (q rows 0..127)
            f32x4 acc[4];
#pragma unroll
            for (int m = 0; m < 4; ++m) acc[m] = f32x4{0.f, 0.f, 0.f, 0.f};
            for (int ksi = 0; ksi < 4; ++ksi) {
                bf16x8 ahi[4], alo[4];
#pragma unroll
                for (int m = 0; m < 4; ++m)
                    load_afrag(xs, m * 16 + fr, ksi, ahi[m], alo[m]);
                bf16x8 bhi, blo;
                load_bfrag(wqkv, wv * 16 + fr, ksi, bhi, blo);
#pragma unroll
                for (int m = 0; m < 4; ++m) {
                    acc[m] = __builtin_amdgcn_mfma_f32_16x16x32_bf16(ahi[m], bhi, acc[m], 0, 0, 0);
                    acc[m] = __builtin_amdgcn_mfma_f32_16x16x32_bf16(ahi[m], blo, acc[m], 0, 0, 0);
                    acc[m] = __builtin_amdgcn_mfma_f32_16x16x32_bf16(alo[m], bhi, acc[m], 0, 0, 0);
                }
            }
            const int ch = wv * 16 + fr;
#pragma unroll
            for (int m = 0; m < 4; ++m)
#pragma unroll
                for (int e = 0; e < 4; ++e) {
                    const int t = m * 16 + fg * 4 + e;
                    qs[t][ch] = fmaxf(acc[m][e], 0.f);
                }
        }
        __syncthreads();

        // Cz: zinv[t][h] = 1/(sum_c q*s + eps); threads 0..255 (waves 0-3)
        if (tid < 256) {
            const int t = tid >> 2, h = tid & 3;
            float z = 0.f;
#pragma unroll
            for (int c4 = 0; c4 < 8; ++c4) {
                const float4 qv = ((const float4*)(&qs[t][h * 32]))[c4];
                const float4 sv = ((const float4*)(&ss[h][0]))[c4];
                z = fmaf(qv.x, sv.x, z);
                z = fmaf(qv.y, sv.y, z);
                z = fmaf(qv.z, sv.z, z);
                z = fmaf(qv.w, sv.w, z);
            }
            zs[t][h] = 1.f / (z + 1e-6f);
        }
        __syncthreads();

        {   // Cy: Y[t][j] = (sum_c q[t][h,c]*kv[h][c][d]) * zinv -> vs (swizzled)
            const int tq = tid >> 7, j = tid & 127;
            const int h = j >> 5, d = j & 31;
            float kvcol[32];
#pragma unroll
            for (int c = 0; c < 32; ++c) kvcol[c] = kvs[h][c][d];
            for (int tt = 0; tt < 16; ++tt) {
                const int t = tq * 16 + tt;
                float y = 0.f;
                const float4* qp = (const float4*)(&qs[t][h * 32]);
#pragma unroll
                for (int c4 = 0; c4 < 8; ++c4) {
                    const float4 qv = qp[c4];
                    y = fmaf(qv.x, kvcol[c4 * 4 + 0], y);
                    y = fmaf(qv.y, kvcol[c4 * 4 + 1], y);
                    y = fmaf(qv.z, kvcol[c4 * 4 + 2], y);
                    y = fmaf(qv.w, kvcol[c4 * 4 + 3], y);
                }
                vs[t * C + (j ^ ((t & 7) << 2))] = y * zs[t][h];
            }
        }
        __syncthreads();

        {   // D: proj GEMM: wave wv -> ntile wv; A = Y (swizzled in vs)
            f32x4 acc[4];
#pragma unroll
            for (int m = 0; m < 4; ++m) acc[m] = f32x4{0.f, 0.f, 0.f, 0.f};
            for (int ksi = 0; ksi < 4; ++ksi) {
                bf16x8 ahi[4], alo[4];
#pragma unroll
                for (int m = 0; m < 4; ++m)
                    load_afrag(vs, m * 16 + fr, ksi, ahi[m], alo[m]);
                bf16x8 bhi, blo;
                load_bfrag(wproj, wv * 16 + fr, ksi, bhi, blo);
#pragma unroll
                for (int m = 0; m < 4; ++m) {
                    acc[m] = __builtin_amdgcn_mfma_f32_16x16x32_bf16(ahi[m], bhi, acc[m], 0, 0, 0);
                    acc[m] = __builtin_amdgcn_mfma_f32_16x16x32_bf16(ahi[m], blo, acc[m], 0, 0, 0);
                    acc[m] = __builtin_amdgcn_mfma_f32_16x16x32_bf16(alo[m], bhi, acc[m], 0, 0, 0);
                }
            }
            const int ch = wv * 16 + fr;
            const float b = bproj[ch];
#pragma unroll
            for (int m = 0; m < 4; ++m)
#pragma unroll
                for (int e = 0; e < 4; ++e) {
                    const int t = m * 16 + fg * 4 + e;
                    if (t < tc)
                        out[(size_t)(beg + t0 + t) * C + ch] = acc[m][e] + b;
                }
        }
    }
#undef STAGE
}

extern "C" void kernel_launch(void* const* d_in, const int* in_sizes, int n_in,
                              void* d_out, int out_size, void* d_ws, size_t ws_size,
                              hipStream_t stream)
{
    const float* x       = (const float*)d_in[0];
    const float* wqkv    = (const float*)d_in[1];
    const float* wproj   = (const float*)d_in[2];
    const float* bproj   = (const float*)d_in[3];
    const int*   offsets = (const int*)d_in[5];
    float* out = (float*)d_out;

    hipLaunchKernelGGL(sla_mfma, dim3(NWIN), dim3(BLK), 0, stream,
                       x, wqkv, wproj, bproj, offsets, out);
}

// Round 4
// 145.512 us; speedup vs baseline: 2.7879x; 1.1242x over previous
//
#include <hip/hip_runtime.h>

namespace {
constexpr int C    = 128;
constexpr int T    = 64;    // token chunk
constexpr int BLK  = 512;   // 8 waves
constexpr int NWIN = 1024;
}

typedef __attribute__((ext_vector_type(8))) short bf16x8;
typedef __attribute__((ext_vector_type(4))) short sh4;
typedef __attribute__((ext_vector_type(4))) float f32x4;

__device__ __forceinline__ short bf16hi(float f) {
    unsigned u = __float_as_uint(f);
    u += 0x7fffu + ((u >> 16) & 1u);           // RNE
    return (short)(u >> 16);
}
__device__ __forceinline__ float bf16f(short h) {
    return __uint_as_float(((unsigned)(unsigned short)h) << 16);
}
__device__ __forceinline__ void split1(float f, short& hi, short& lo) {
    hi = bf16hi(f);
    lo = bf16hi(f - bf16f(hi));
}

// Pre-split weights into ws: [0..65535] = hi, [65536..131071] = lo,
// index = row-major concat of wqkv (384x128) then wproj (128x128).
__global__ void prep_weights(const float* __restrict__ wqkv,
                             const float* __restrict__ wproj,
                             short* __restrict__ wsp) {
    const int i = blockIdx.x * 256 + threadIdx.x;   // 0..65535
    const float f = (i < 49152) ? wqkv[i] : wproj[i - 49152];
    short hi, lo;
    split1(f, hi, lo);
    wsp[i] = hi;
    wsp[65536 + i] = lo;
}

// One block per window, 512 threads = 8 waves. LDS ~117.5KB -> 1 block/CU.
template <bool PRE>
__global__ __launch_bounds__(BLK)
void sla_mfma2(const float* __restrict__ x,        // [N][128]
               const float* __restrict__ wqkv,     // [384][128]
               const float* __restrict__ wproj,    // [128][128]
               const float* __restrict__ bproj,    // [128]
               const int*   __restrict__ offsets,  // [1025]
               const short* __restrict__ wsp,      // pre-split weights (PRE)
               float*       __restrict__ out)      // [N][128]
{
    __shared__ __align__(16) short xs_hi[T * C], xs_lo[T * C];   // x, swz1
    __shared__ __align__(16) short ldsA[2 * T * C];  // pass1: kT hi|lo [ch][t] swz2 ; pass2: q hi|lo [t][c] swz1
    __shared__ __align__(16) short ldsB[2 * T * C];  // pass1: vT hi|lo ; pass2: yn hi|lo
    __shared__ __align__(16) short kvT_hi[4 * 32 * 32], kvT_lo[4 * 32 * 32]; // [h][d][c]
    __shared__ float s_part[128][8];
    __shared__ float ss[128];          // s[h*32+c]
    __shared__ float zs[T * 4];        // zinv[t][h]

    const int win = blockIdx.x;
    const int beg = offsets[win];
    const int cnt = offsets[win + 1] - beg;
    if (cnt <= 0) return;
    const int nch = (cnt + T - 1) / T;

    const int tid = threadIdx.x;
    const int wv = tid >> 6, ln = tid & 63;
    const int fr = ln & 15, fg = ln >> 4;
    const int mh = wv & 1, ng = wv >> 1;    // GEMM wave mapping
    const int hw = wv >> 1, tw = wv & 1;    // kv / y wave mapping

    short* kT_hi = ldsA;  short* kT_lo = ldsA + T * C;
    short* vT_hi = ldsB;  short* vT_lo = ldsB + T * C;
    short* q_hi  = ldsA;  short* q_lo  = ldsA + T * C;
    short* yn_hi = ldsB;  short* yn_lo = ldsB + T * C;

    auto loadB = [&](int row512, int koff, bf16x8& bhi, bf16x8& blo) {
        if constexpr (PRE) {
            const int idx = row512 * C + koff;
            bhi = *(const bf16x8*)(wsp + idx);
            blo = *(const bf16x8*)(wsp + 65536 + idx);
        } else {
            const float* p = (row512 < 384) ? (wqkv + (size_t)row512 * C + koff)
                                            : (wproj + (size_t)(row512 - 384) * C + koff);
            const float4 a = *(const float4*)p;
            const float4 b = *(const float4*)(p + 4);
            const float f[8] = {a.x, a.y, a.z, a.w, b.x, b.y, b.z, b.w};
#pragma unroll
            for (int u = 0; u < 8; ++u) {
                short h_, l_;
                split1(f[u], h_, l_);
                bhi[u] = h_; blo[u] = l_;
            }
        }
    };

    auto stage = [&](int t0, int tc) {
        for (int i = tid; i < T * 16; i += BLK) {
            const int t = i >> 4, c8 = (i & 15) << 3;
            float4 a = {0.f, 0.f, 0.f, 0.f}, b = {0.f, 0.f, 0.f, 0.f};
            if (t < tc) {
                const float* p = x + (size_t)(beg + t0 + t) * C + c8;
                a = *(const float4*)p;
                b = *(const float4*)(p + 4);
            }
            const float f[8] = {a.x, a.y, a.z, a.w, b.x, b.y, b.z, b.w};
            bf16x8 hi, lo;
#pragma unroll
            for (int u = 0; u < 8; ++u) {
                short h_, l_;
                split1(f[u], h_, l_);
                hi[u] = h_; lo[u] = l_;
            }
            const int s = t * C + (c8 ^ ((t & 7) << 3));
            *(bf16x8*)(xs_hi + s) = hi;
            *(bf16x8*)(xs_lo + s) = lo;
        }
    };

    f32x4 kvacc[2] = {{0.f,0.f,0.f,0.f},{0.f,0.f,0.f,0.f}};
    float sacc = 0.f;

    // =================== PASS 1: k,v GEMM -> kv-MFMA, s ===================
    for (int c0 = 0; c0 < nch; ++c0) {
        const int t0 = c0 * T;
        const int tc = (cnt - t0 < T) ? (cnt - t0) : T;
        if (c0 > 0) __syncthreads();
        stage(t0, tc);
        __syncthreads();

        {   // G1: wave (mh, ng): m-tiles {2mh,2mh+1}, ntiles {4ng..4ng+3} of [k(8) v(8)]
            f32x4 acc[2][4];
#pragma unroll
            for (int mi = 0; mi < 2; ++mi)
#pragma unroll
                for (int ni = 0; ni < 4; ++ni) acc[mi][ni] = f32x4{0.f, 0.f, 0.f, 0.f};
#pragma unroll
            for (int ksi = 0; ksi < 4; ++ksi) {
                const int koff = ksi * 32 + fg * 8;
                bf16x8 ahi[2], alo[2];
#pragma unroll
                for (int mi = 0; mi < 2; ++mi) {
                    const int row = (2 * mh + mi) * 16 + fr;
                    const int s = row * C + (koff ^ ((row & 7) << 3));
                    ahi[mi] = *(const bf16x8*)(xs_hi + s);
                    alo[mi] = *(const bf16x8*)(xs_lo + s);
                }
#pragma unroll
                for (int ni = 0; ni < 4; ++ni) {
                    bf16x8 bhi, blo;
                    loadB(128 + (4 * ng + ni) * 16 + fr, koff, bhi, blo);
#pragma unroll
                    for (int mi = 0; mi < 2; ++mi) {
                        acc[mi][ni] = __builtin_amdgcn_mfma_f32_16x16x32_bf16(ahi[mi], bhi, acc[mi][ni], 0, 0, 0);
                        acc[mi][ni] = __builtin_amdgcn_mfma_f32_16x16x32_bf16(ahi[mi], blo, acc[mi][ni], 0, 0, 0);
                        acc[mi][ni] = __builtin_amdgcn_mfma_f32_16x16x32_bf16(alo[mi], bhi, acc[mi][ni], 0, 0, 0);
                    }
                }
            }
            // epilogue: relu(k), transpose-store hi/lo packed b64, s-partials
#pragma unroll
            for (int ni = 0; ni < 4; ++ni) {
                const int nt = 4 * ng + ni;
                const bool isk = (nt < 8);
                const int ch = (isk ? nt : nt - 8) * 16 + fr;
                float sp = 0.f;
#pragma unroll
                for (int mi = 0; mi < 2; ++mi) {
                    const int tb = (2 * mh + mi) * 16 + fg * 4;
                    sh4 hi4, lo4;
#pragma unroll
                    for (int e = 0; e < 4; ++e) {
                        float v = acc[mi][ni][e];
                        if (isk) { v = fmaxf(v, 0.f); sp += v; }
                        short h_, l_;
                        split1(v, h_, l_);
                        hi4[e] = h_; lo4[e] = l_;
                    }
                    const int s = ch * T + (tb ^ ((ch & 7) << 3));
                    if (isk) { *(sh4*)(kT_hi + s) = hi4; *(sh4*)(kT_lo + s) = lo4; }
                    else     { *(sh4*)(vT_hi + s) = hi4; *(sh4*)(vT_lo + s) = lo4; }
                }
                if (isk) s_part[ch][mh * 4 + fg] = sp;
            }
        }
        __syncthreads();

        {   // KV-MFMA: wave (hw, tw): kv[hw][c=tw*16+..][d] += kT^T v ; K = t (64)
#pragma unroll
            for (int kt = 0; kt < 2; ++kt) {
                const int t8 = kt * 32 + fg * 8;
                const int ra = hw * 32 + tw * 16 + fr;
                const int sa = ra * T + (t8 ^ ((ra & 7) << 3));
                const bf16x8 ahi = *(const bf16x8*)(kT_hi + sa);
                const bf16x8 alo = *(const bf16x8*)(kT_lo + sa);
#pragma unroll
                for (int dt = 0; dt < 2; ++dt) {
                    const int rb = hw * 32 + dt * 16 + fr;
                    const int sb = rb * T + (t8 ^ ((rb & 7) << 3));
                    const bf16x8 bhi = *(const bf16x8*)(vT_hi + sb);
                    const bf16x8 blo = *(const bf16x8*)(vT_lo + sb);
                    kvacc[dt] = __builtin_amdgcn_mfma_f32_16x16x32_bf16(ahi, bhi, kvacc[dt], 0, 0, 0);
                    kvacc[dt] = __builtin_amdgcn_mfma_f32_16x16x32_bf16(ahi, blo, kvacc[dt], 0, 0, 0);
                    kvacc[dt] = __builtin_amdgcn_mfma_f32_16x16x32_bf16(alo, bhi, kvacc[dt], 0, 0, 0);
                }
            }
            if (tid < 128) {
                float t = 0.f;
#pragma unroll
                for (int jj = 0; jj < 8; ++jj) t += s_part[tid][jj];
                sacc += t;
            }
        }
    }

    // KV epilogue: kvacc -> kvT bf16 hi/lo [h][d][c]; ss
    {
#pragma unroll
        for (int dt = 0; dt < 2; ++dt) {
            const int d = dt * 16 + fr;
            const int cb = tw * 16 + fg * 4;
            sh4 hi4, lo4;
#pragma unroll
            for (int e = 0; e < 4; ++e) {
                short h_, l_;
                split1(kvacc[dt][e], h_, l_);
                hi4[e] = h_; lo4[e] = l_;
            }
            const int s = hw * 1024 + d * 32 + cb;
            *(sh4*)(kvT_hi + s) = hi4;
            *(sh4*)(kvT_lo + s) = lo4;
        }
        if (tid < 128) ss[tid] = sacc;
    }
    __syncthreads();

    // =================== PASS 2: q GEMM -> z -> y-MFMA -> proj ===================
    for (int c0 = 0; c0 < nch; ++c0) {
        const int t0 = c0 * T;
        const int tc = (cnt - t0 < T) ? (cnt - t0) : T;
        if (nch > 1) {          // nch==1: xs still holds chunk 0 from pass 1
            stage(t0, tc);
            __syncthreads();
        }

        {   // Q GEMM: wave (mh, ng): m {2mh,2mh+1}, ntiles {2ng,2ng+1}
            f32x4 acc[2][2];
#pragma unroll
            for (int mi = 0; mi < 2; ++mi)
#pragma unroll
                for (int ni = 0; ni < 2; ++ni) acc[mi][ni] = f32x4{0.f, 0.f, 0.f, 0.f};
#pragma unroll
            for (int ksi = 0; ksi < 4; ++ksi) {
                const int koff = ksi * 32 + fg * 8;
                bf16x8 ahi[2], alo[2];
#pragma unroll
                for (int mi = 0; mi < 2; ++mi) {
                    const int row = (2 * mh + mi) * 16 + fr;
                    const int s = row * C + (koff ^ ((row & 7) << 3));
                    ahi[mi] = *(const bf16x8*)(xs_hi + s);
                    alo[mi] = *(const bf16x8*)(xs_lo + s);
                }
#pragma unroll
                for (int ni = 0; ni < 2; ++ni) {
                    bf16x8 bhi, blo;
                    loadB((2 * ng + ni) * 16 + fr, koff, bhi, blo);
#pragma unroll
                    for (int mi = 0; mi < 2; ++mi) {
                        acc[mi][ni] = __builtin_amdgcn_mfma_f32_16x16x32_bf16(ahi[mi], bhi, acc[mi][ni], 0, 0, 0);
                        acc[mi][ni] = __builtin_amdgcn_mfma_f32_16x16x32_bf16(ahi[mi], blo, acc[mi][ni], 0, 0, 0);
                        acc[mi][ni] = __builtin_amdgcn_mfma_f32_16x16x32_bf16(alo[mi], bhi, acc[mi][ni], 0, 0, 0);
                    }
                }
            }
            // epilogue: relu, split, store q [t][c] swz1 (scalar b16)
#pragma unroll
            for (int ni = 0; ni < 2; ++ni) {
                const int ch = (2 * ng + ni) * 16 + fr;
#pragma unroll
                for (int mi = 0; mi < 2; ++mi)
#pragma unroll
                    for (int e = 0; e < 4; ++e) {
                        const int t = (2 * mh + mi) * 16 + fg * 4 + e;
                        const float v = fmaxf(acc[mi][ni][e], 0.f);
                        short h_, l_;
                        split1(v, h_, l_);
                        const int s = t * C + (ch ^ ((t & 7) << 3));
                        q_hi[s] = h_;
                        q_lo[s] = l_;
                    }
            }
        }
        __syncthreads();

        // CZ: zinv[t][h] = 1/(q . s + eps)
        if (tid < 256) {
            const int t = tid >> 2, h = tid & 3;
            float z = 0.f;
#pragma unroll
            for (int c8 = 0; c8 < 4; ++c8) {
                const int cb = h * 32 + c8 * 8;
                const int s = t * C + (cb ^ ((t & 7) << 3));
                const bf16x8 qh = *(const bf16x8*)(q_hi + s);
                const bf16x8 ql = *(const bf16x8*)(q_lo + s);
#pragma unroll
                for (int u = 0; u < 8; ++u)
                    z += (bf16f(qh[u]) + bf16f(ql[u])) * ss[cb + u];
            }
            zs[t * 4 + h] = 1.f / (z + 1e-6f);
        }
        __syncthreads();

        {   // Y-MFMA: wave (hw, tw): y[t][hw*32+tw*16+fr], K = c (32)
            f32x4 acc[4];
#pragma unroll
            for (int m = 0; m < 4; ++m) acc[m] = f32x4{0.f, 0.f, 0.f, 0.f};
            const int koff = fg * 8;
            const int rb = tw * 16 + fr;
            const bf16x8 bhi = *(const bf16x8*)(kvT_hi + hw * 1024 + rb * 32 + koff);
            const bf16x8 blo = *(const bf16x8*)(kvT_lo + hw * 1024 + rb * 32 + koff);
#pragma unroll
            for (int m = 0; m < 4; ++m) {
                const int row = m * 16 + fr;
                const int s = row * C + ((hw * 32 + koff) ^ ((row & 7) << 3));
                const bf16x8 ahi = *(const bf16x8*)(q_hi + s);
                const bf16x8 alo = *(const bf16x8*)(q_lo + s);
                acc[m] = __builtin_amdgcn_mfma_f32_16x16x32_bf16(ahi, bhi, acc[m], 0, 0, 0);
                acc[m] = __builtin_amdgcn_mfma_f32_16x16x32_bf16(ahi, blo, acc[m], 0, 0, 0);
                acc[m] = __builtin_amdgcn_mfma_f32_16x16x32_bf16(alo, bhi, acc[m], 0, 0, 0);
            }
            // epilogue: yn = y * zinv -> split -> yn [t][c] swz1
            const int ych = hw * 32 + tw * 16 + fr;
#pragma unroll
            for (int m = 0; m < 4; ++m)
#pragma unroll
                for (int e = 0; e < 4; ++e) {
                    const int t = m * 16 + fg * 4 + e;
                    const float yv = acc[m][e] * zs[t * 4 + hw];
                    short h_, l_;
                    split1(yv, h_, l_);
                    const int s = t * C + (ych ^ ((t & 7) << 3));
                    yn_hi[s] = h_;
                    yn_lo[s] = l_;
                }
        }
        __syncthreads();

        {   // PROJ: wave (mh, ng): ntiles {2ng,2ng+1}
            f32x4 acc[2][2];
#pragma unroll
            for (int mi = 0; mi < 2; ++mi)
#pragma unroll
                for (int ni = 0; ni < 2; ++ni) acc[mi][ni] = f32x4{0.f, 0.f, 0.f, 0.f};
#pragma unroll
            for (int ksi = 0; ksi < 4; ++ksi) {
                const int koff = ksi * 32 + fg * 8;
                bf16x8 ahi[2], alo[2];
#pragma unroll
                for (int mi = 0; mi < 2; ++mi) {
                    const int row = (2 * mh + mi) * 16 + fr;
                    const int s = row * C + (koff ^ ((row & 7) << 3));
                    ahi[mi] = *(const bf16x8*)(yn_hi + s);
                    alo[mi] = *(const bf16x8*)(yn_lo + s);
                }
#pragma unroll
                for (int ni = 0; ni < 2; ++ni) {
                    bf16x8 bhi, blo;
                    loadB(384 + (2 * ng + ni) * 16 + fr, koff, bhi, blo);
#pragma unroll
                    for (int mi = 0; mi < 2; ++mi) {
                        acc[mi][ni] = __builtin_amdgcn_mfma_f32_16x16x32_bf16(ahi[mi], bhi, acc[mi][ni], 0, 0, 0);
                        acc[mi][ni] = __builtin_amdgcn_mfma_f32_16x16x32_bf16(ahi[mi], blo, acc[mi][ni], 0, 0, 0);
                        acc[mi][ni] = __builtin_amdgcn_mfma_f32_16x16x32_bf16(alo[mi], bhi, acc[mi][ni], 0, 0, 0);
                    }
                }
            }
#pragma unroll
            for (int ni = 0; ni < 2; ++ni) {
                const int ch = (2 * ng + ni) * 16 + fr;
                const float b = bproj[ch];
#pragma unroll
                for (int mi = 0; mi < 2; ++mi)
#pragma unroll
                    for (int e = 0; e < 4; ++e) {
                        const int t = (2 * mh + mi) * 16 + fg * 4 + e;
                        if (t < tc)
                            out[(size_t)(beg + t0 + t) * C + ch] = acc[mi][ni][e] + b;
                    }
            }
        }
        if (c0 + 1 < nch) __syncthreads();
    }
}

extern "C" void kernel_launch(void* const* d_in, const int* in_sizes, int n_in,
                              void* d_out, int out_size, void* d_ws, size_t ws_size,
                              hipStream_t stream)
{
    const float* x       = (const float*)d_in[0];
    const float* wqkv    = (const float*)d_in[1];
    const float* wproj   = (const float*)d_in[2];
    const float* bproj   = (const float*)d_in[3];
    const int*   offsets = (const int*)d_in[5];
    float* out = (float*)d_out;
    short* wsp = (short*)d_ws;

    const bool pre = (ws_size >= 131072u * sizeof(short));
    if (pre) {
        hipLaunchKernelGGL(prep_weights, dim3(256), dim3(256), 0, stream, wqkv, wproj, wsp);
        hipLaunchKernelGGL((sla_mfma2<true>), dim3(NWIN), dim3(BLK), 0, stream,
                           x, wqkv, wproj, bproj, offsets, wsp, out);
    } else {
        hipLaunchKernelGGL((sla_mfma2<false>), dim3(NWIN), dim3(BLK), 0, stream,
                           x, wqkv, wproj, bproj, offsets, wsp, out);
    }
}

// Round 6
// 134.623 us; speedup vs baseline: 3.0134x; 1.0809x over previous
//
#include <hip/hip_runtime.h>

namespace {
constexpr int C     = 128;
constexpr int T     = 64;    // token chunk
constexpr int BLK   = 512;   // 8 waves
constexpr int NWIN  = 1024;
constexpr int KVSTR = 40;    // kvs row stride (elems): 16B-aligned rows, ~2-way banks
}

typedef __attribute__((ext_vector_type(8))) short bf16x8;
typedef __attribute__((ext_vector_type(4))) short sh4;
typedef __attribute__((ext_vector_type(4))) float f32x4;

__device__ __forceinline__ short bf16rne(float f) {
    unsigned u = __float_as_uint(f);
    u += 0x7fffu + ((u >> 16) & 1u);
    return (short)(u >> 16);
}
__device__ __forceinline__ float bf16f(short h) {
    return __uint_as_float(((unsigned)(unsigned short)h) << 16);
}
__device__ __forceinline__ void split1(float f, short& hi, short& lo) {
    hi = bf16rne(f);
    lo = bf16rne(f - bf16f(hi));
}

// Pre-split weights: [0..65535]=hi, [65536..131071]=lo; rows = wqkv(384) ++ wproj(128).
__global__ void prep_weights(const float* __restrict__ wqkv,
                             const float* __restrict__ wproj,
                             short* __restrict__ wsp) {
    const int i = blockIdx.x * 256 + threadIdx.x;   // 0..65535
    const float f = (i < 49152) ? wqkv[i] : wproj[i - 49152];
    short hi, lo;
    split1(f, hi, lo);
    wsp[i] = hi;
    wsp[65536 + i] = lo;
}

// One block per window, 8 waves. LDS ~74.5KB -> 2 blocks/CU (16 waves/CU).
// Precision: x & weights hi/lo split; k,v,q,yn,kv single-bf16 RNE; s,z,acc fp32.
template <bool PRE>
__global__ __launch_bounds__(BLK, 4)
void sla4(const float* __restrict__ x,        // [N][128]
          const float* __restrict__ wqkv,     // [384][128]
          const float* __restrict__ wproj,    // [128][128]
          const float* __restrict__ bproj,    // [128]
          const int*   __restrict__ offsets,  // [1025]
          const short* __restrict__ wsp,      // pre-split weights (PRE)
          float*       __restrict__ out)      // [N][128]
{
    __shared__ __align__(16) short xs_hi[T * C];       // 16KB  x hi, [t][c] swz
    __shared__ __align__(16) short xs_lo[T * C];       // 16KB  x lo
    __shared__ __align__(16) short kTq[C * T];         // 16KB  p1: kT[ch][t] swz | p2: q[t][c] swz
    __shared__ __align__(16) short vTy[C * T];         // 16KB  p1: vT[ch][t] swz | p2: yn[t][c] swz
    __shared__ __align__(16) short kvs[4 * 32 * KVSTR];// 10KB  kv[h][d][c] bf16, padded rows
    __shared__ float ss[C];                            // s[h*32+c]

    const int win = blockIdx.x;
    const int beg = offsets[win];
    const int cnt = offsets[win + 1] - beg;
    if (cnt <= 0) return;
    const int nch = (cnt + T - 1) / T;

    const int tid = threadIdx.x;
    const int wv = tid >> 6, ln = tid & 63;
    const int fr = ln & 15, fg = ln >> 4;

    auto loadB = [&](int row512, int koff, bf16x8& bhi, bf16x8& blo) {
        if constexpr (PRE) {
            const int idx = row512 * C + koff;
            bhi = *(const bf16x8*)(wsp + idx);
            blo = *(const bf16x8*)(wsp + 65536 + idx);
        } else {
            const float* p = (row512 < 384) ? (wqkv + (size_t)row512 * C + koff)
                                            : (wproj + (size_t)(row512 - 384) * C + koff);
            const float4 a = *(const float4*)p;
            const float4 b = *(const float4*)(p + 4);
            const float f[8] = {a.x, a.y, a.z, a.w, b.x, b.y, b.z, b.w};
#pragma unroll
            for (int u = 0; u < 8; ++u) { short h_, l_; split1(f[u], h_, l_); bhi[u] = h_; blo[u] = l_; }
        }
    };

    auto stage = [&](int t0, int tc) {
#pragma unroll
        for (int it = 0; it < 2; ++it) {
            const int i = tid + it * BLK;          // < 1024
            const int t = i >> 4, c8 = (i & 15) << 3;
            float4 a = {0.f, 0.f, 0.f, 0.f}, b = {0.f, 0.f, 0.f, 0.f};
            if (t < tc) {
                const float* p = x + (size_t)(beg + t0 + t) * C + c8;
                a = *(const float4*)p;
                b = *(const float4*)(p + 4);
            }
            const float f[8] = {a.x, a.y, a.z, a.w, b.x, b.y, b.z, b.w};
            bf16x8 hi, lo;
#pragma unroll
            for (int u = 0; u < 8; ++u) { short h_, l_; split1(f[u], h_, l_); hi[u] = h_; lo[u] = l_; }
            const int s = t * C + (c8 ^ ((t & 7) << 3));
            *(bf16x8*)(xs_hi + s) = hi;
            *(bf16x8*)(xs_lo + s) = lo;
        }
    };

    // persistent accumulators (KV phase): wave (aH=wv>>1 head, tw=wv&1 c-tile)
    const int aH = wv >> 1, tw = wv & 1;
    f32x4 kvacc[2] = {{0.f,0.f,0.f,0.f},{0.f,0.f,0.f,0.f}};
    f32x4 sacc = {0.f, 0.f, 0.f, 0.f};
    bf16x8 ones;
#pragma unroll
    for (int u = 0; u < 8; ++u) ones[u] = (short)0x3F80;

    // =================== PASS 1: {stage | G1 k,v | KV+s} per chunk ===================
    for (int c0 = 0; c0 < nch; ++c0) {
        const int t0 = c0 * T;
        const int tc = (cnt - t0 < T) ? (cnt - t0) : T;
        stage(t0, tc);
        __syncthreads();

        {   // G1: wave -> ntiles {2wv, 2wv+1} of 16 [k(0..7) v(8..15)], all 4 m-tiles
            f32x4 acc[2][4];
#pragma unroll
            for (int ni = 0; ni < 2; ++ni)
#pragma unroll
                for (int m = 0; m < 4; ++m) acc[ni][m] = f32x4{0.f, 0.f, 0.f, 0.f};
#pragma unroll
            for (int ksi = 0; ksi < 4; ++ksi) {
                const int koff = ksi * 32 + fg * 8;
                bf16x8 ahi[4], alo[4];
#pragma unroll
                for (int m = 0; m < 4; ++m) {
                    const int row = m * 16 + fr;
                    const int s = row * C + (koff ^ ((row & 7) << 3));
                    ahi[m] = *(const bf16x8*)(xs_hi + s);
                    alo[m] = *(const bf16x8*)(xs_lo + s);
                }
#pragma unroll
                for (int ni = 0; ni < 2; ++ni) {
                    bf16x8 bhi, blo;
                    loadB(128 + (2 * wv + ni) * 16 + fr, koff, bhi, blo);
#pragma unroll
                    for (int m = 0; m < 4; ++m) {
                        acc[ni][m] = __builtin_amdgcn_mfma_f32_16x16x32_bf16(ahi[m], bhi, acc[ni][m], 0, 0, 0);
                        acc[ni][m] = __builtin_amdgcn_mfma_f32_16x16x32_bf16(ahi[m], blo, acc[ni][m], 0, 0, 0);
                        acc[ni][m] = __builtin_amdgcn_mfma_f32_16x16x32_bf16(alo[m], bhi, acc[ni][m], 0, 0, 0);
                    }
                }
            }
            // epilogue: relu(k) -> kT[ch][t]; v -> vT[ch][t]; b64-packed, swz on t-granule
#pragma unroll
            for (int ni = 0; ni < 2; ++ni) {
                const int nt = 2 * wv + ni;
                const bool isk = (nt < 8);
                const int ch = (isk ? nt : nt - 8) * 16 + fr;
                short* dst = isk ? kTq : vTy;
#pragma unroll
                for (int m = 0; m < 4; ++m) {
                    sh4 h4;
#pragma unroll
                    for (int e = 0; e < 4; ++e) {
                        float v = acc[ni][m][e];
                        if (isk) v = fmaxf(v, 0.f);
                        h4[e] = bf16rne(v);
                    }
                    const int tb = m * 16 + fg * 4;
                    *(sh4*)(dst + ch * T + (tb ^ ((ch & 7) << 3))) = h4;
                }
            }
        }
        __syncthreads();

        {   // KV: kv[aH][c][d] += kT^T v (K=64); s via ones-column MFMA
#pragma unroll
            for (int kt = 0; kt < 2; ++kt) {
                const int t8 = kt * 32 + fg * 8;
                const int cch = aH * 32 + tw * 16 + fr;
                const bf16x8 a8 = *(const bf16x8*)(kTq + cch * T + (t8 ^ ((cch & 7) << 3)));
                sacc = __builtin_amdgcn_mfma_f32_16x16x32_bf16(a8, ones, sacc, 0, 0, 0);
#pragma unroll
                for (int dt = 0; dt < 2; ++dt) {
                    const int dch = aH * 32 + dt * 16 + fr;
                    const bf16x8 b8 = *(const bf16x8*)(vTy + dch * T + (t8 ^ ((dch & 7) << 3)));
                    kvacc[dt] = __builtin_amdgcn_mfma_f32_16x16x32_bf16(a8, b8, kvacc[dt], 0, 0, 0);
                }
            }
        }
        if (c0 + 1 < nch) __syncthreads();
    }

    // KV epilogue: kv(acc D[m=c][n=d]) -> kvs[h][d][c] bf16; s -> ss
    {
#pragma unroll
        for (int dt = 0; dt < 2; ++dt) {
            const int d = dt * 16 + fr;
#pragma unroll
            for (int e = 0; e < 4; ++e) {
                const int c = tw * 16 + fg * 4 + e;
                kvs[aH * (32 * KVSTR) + d * KVSTR + c] = bf16rne(kvacc[dt][e]);
            }
        }
        if (fr == 0) {
#pragma unroll
            for (int e = 0; e < 4; ++e)
                ss[aH * 32 + tw * 16 + fg * 4 + e] = sacc[e];
        }
    }

    // =================== PASS 2: {stage? | Q | Y(z in-wave) | PROJ} per chunk ===================
    for (int c0 = 0; c0 < nch; ++c0) {
        const int t0 = c0 * T;
        const int tc = (cnt - t0 < T) ? (cnt - t0) : T;
        if (nch > 1) stage(t0, tc);     // nch==1: xs from pass1 still valid
        __syncthreads();                // also publishes kvs/ss on first iteration

        {   // Q: wave -> ntile wv; q rows 0..127
            f32x4 acc[4];
#pragma unroll
            for (int m = 0; m < 4; ++m) acc[m] = f32x4{0.f, 0.f, 0.f, 0.f};
#pragma unroll
            for (int ksi = 0; ksi < 4; ++ksi) {
                const int koff = ksi * 32 + fg * 8;
                bf16x8 ahi[4], alo[4];
#pragma unroll
                for (int m = 0; m < 4; ++m) {
                    const int row = m * 16 + fr;
                    const int s = row * C + (koff ^ ((row & 7) << 3));
                    ahi[m] = *(const bf16x8*)(xs_hi + s);
                    alo[m] = *(const bf16x8*)(xs_lo + s);
                }
                bf16x8 bhi, blo;
                loadB(wv * 16 + fr, koff, bhi, blo);
#pragma unroll
                for (int m = 0; m < 4; ++m) {
                    acc[m] = __builtin_amdgcn_mfma_f32_16x16x32_bf16(ahi[m], bhi, acc[m], 0, 0, 0);
                    acc[m] = __builtin_amdgcn_mfma_f32_16x16x32_bf16(ahi[m], blo, acc[m], 0, 0, 0);
                    acc[m] = __builtin_amdgcn_mfma_f32_16x16x32_bf16(alo[m], bhi, acc[m], 0, 0, 0);
                }
            }
            const int ch = wv * 16 + fr;
#pragma unroll
            for (int m = 0; m < 4; ++m)
#pragma unroll
                for (int e = 0; e < 4; ++e) {
                    const int t = m * 16 + fg * 4 + e;
                    kTq[t * C + (ch ^ ((t & 7) << 3))] = bf16rne(fmaxf(acc[m][e], 0.f));
                }
        }
        __syncthreads();

        {   // Y: wave (a = wv>>1 head, mp = wv&1 t-half); z computed in-wave, shfl-broadcast
            const int a = wv >> 1, mp = wv & 1;
            bf16x8 bfr[2];
#pragma unroll
            for (int dl = 0; dl < 2; ++dl)
                bfr[dl] = *(const bf16x8*)(kvs + a * (32 * KVSTR) + (dl * 16 + fr) * KVSTR + fg * 8);

            const float4 s0 = *(const float4*)(ss + a * 32 + fg * 8);
            const float4 s1 = *(const float4*)(ss + a * 32 + fg * 8 + 4);

            bf16x8 afr[2];
            float zinv[2];
#pragma unroll
            for (int mi = 0; mi < 2; ++mi) {
                const int row = (mp * 2 + mi) * 16 + fr;
                const int s = row * C + ((a * 32 + fg * 8) ^ ((row & 7) << 3));
                afr[mi] = *(const bf16x8*)(kTq + s);
                float zp = 0.f;
                zp = fmaf(bf16f(afr[mi][0]), s0.x, zp);
                zp = fmaf(bf16f(afr[mi][1]), s0.y, zp);
                zp = fmaf(bf16f(afr[mi][2]), s0.z, zp);
                zp = fmaf(bf16f(afr[mi][3]), s0.w, zp);
                zp = fmaf(bf16f(afr[mi][4]), s1.x, zp);
                zp = fmaf(bf16f(afr[mi][5]), s1.y, zp);
                zp = fmaf(bf16f(afr[mi][6]), s1.z, zp);
                zp = fmaf(bf16f(afr[mi][7]), s1.w, zp);
                zp += __shfl_xor(zp, 16);     // reduce over fg bit0
                zp += __shfl_xor(zp, 32);     // reduce over fg bit1
                zinv[mi] = 1.f / (zp + 1e-6f);   // all lanes: zinv for (head a, row fr)
            }
            f32x4 acc[2][2];
#pragma unroll
            for (int mi = 0; mi < 2; ++mi)
#pragma unroll
                for (int dl = 0; dl < 2; ++dl) {
                    acc[mi][dl] = f32x4{0.f, 0.f, 0.f, 0.f};
                    acc[mi][dl] = __builtin_amdgcn_mfma_f32_16x16x32_bf16(afr[mi], bfr[dl], acc[mi][dl], 0, 0, 0);
                }
            // epilogue: yn = y * zinv(row fg*4+e via shfl) -> vTy [t][c] swz
#pragma unroll
            for (int mi = 0; mi < 2; ++mi)
#pragma unroll
                for (int e = 0; e < 4; ++e) {
                    const float zt = __shfl(zinv[mi], fg * 4 + e);
                    const int t = (mp * 2 + mi) * 16 + fg * 4 + e;
#pragma unroll
                    for (int dl = 0; dl < 2; ++dl) {
                        const int ch = a * 32 + dl * 16 + fr;
                        vTy[t * C + (ch ^ ((t & 7) << 3))] = bf16rne(acc[mi][dl][e] * zt);
                    }
                }
        }
        __syncthreads();

        {   // PROJ: wave -> ntile wv; A = yn single bf16, B = wproj hi/lo
            f32x4 acc[4];
#pragma unroll
            for (int m = 0; m < 4; ++m) acc[m] = f32x4{0.f, 0.f, 0.f, 0.f};
#pragma unroll
            for (int ksi = 0; ksi < 4; ++ksi) {
                const int koff = ksi * 32 + fg * 8;
                bf16x8 a8[4];
#pragma unroll
                for (int m = 0; m < 4; ++m) {
                    const int row = m * 16 + fr;
                    a8[m] = *(const bf16x8*)(vTy + row * C + (koff ^ ((row & 7) << 3)));
                }
                bf16x8 bhi, blo;
                loadB(384 + wv * 16 + fr, koff, bhi, blo);
#pragma unroll
                for (int m = 0; m < 4; ++m) {
                    acc[m] = __builtin_amdgcn_mfma_f32_16x16x32_bf16(a8[m], bhi, acc[m], 0, 0, 0);
                    acc[m] = __builtin_amdgcn_mfma_f32_16x16x32_bf16(a8[m], blo, acc[m], 0, 0, 0);
                }
            }
            const int ch = wv * 16 + fr;
            const float b = bproj[ch];
#pragma unroll
            for (int m = 0; m < 4; ++m)
#pragma unroll
                for (int e = 0; e < 4; ++e) {
                    const int t = m * 16 + fg * 4 + e;
                    if (t < tc)
                        out[(size_t)(beg + t0 + t) * C + ch] = acc[m][e] + b;
                }
        }
        if (c0 + 1 < nch) __syncthreads();
    }
}

extern "C" void kernel_launch(void* const* d_in, const int* in_sizes, int n_in,
                              void* d_out, int out_size, void* d_ws, size_t ws_size,
                              hipStream_t stream)
{
    const float* x       = (const float*)d_in[0];
    const float* wqkv    = (const float*)d_in[1];
    const float* wproj   = (const float*)d_in[2];
    const float* bproj   = (const float*)d_in[3];
    const int*   offsets = (const int*)d_in[5];
    float* out = (float*)d_out;
    short* wsp = (short*)d_ws;

    const bool pre = (ws_size >= 131072u * sizeof(short));
    if (pre) {
        hipLaunchKernelGGL(prep_weights, dim3(256), dim3(256), 0, stream, wqkv, wproj, wsp);
        hipLaunchKernelGGL((sla4<true>), dim3(NWIN), dim3(BLK), 0, stream,
                           x, wqkv, wproj, bproj, offsets, wsp, out);
    } else {
        hipLaunchKernelGGL((sla4<false>), dim3(NWIN), dim3(BLK), 0, stream,
                           x, wqkv, wproj, bproj, offsets, wsp, out);
    }
}

// Round 7
// 101.288 us; speedup vs baseline: 4.0052x; 1.3291x over previous
//
#include <hip/hip_runtime.h>

namespace {
constexpr int C     = 128;
constexpr int T     = 64;    // token chunk
constexpr int BLK   = 512;   // 8 waves
constexpr int NWIN  = 1024;
constexpr int KVSTR = 40;    // kvs row stride (elems): 16B-aligned rows, ~2-way banks
}

typedef __attribute__((ext_vector_type(8))) short bf16x8;
typedef __attribute__((ext_vector_type(4))) short sh4;
typedef __attribute__((ext_vector_type(4))) float f32x4;

__device__ __forceinline__ short bf16rne(float f) {
    unsigned u = __float_as_uint(f);
    u += 0x7fffu + ((u >> 16) & 1u);
    return (short)(u >> 16);
}
__device__ __forceinline__ float bf16f(short h) {
    return __uint_as_float(((unsigned)(unsigned short)h) << 16);
}
__device__ __forceinline__ void split1(float f, short& hi, short& lo) {
    hi = bf16rne(f);
    lo = bf16rne(f - bf16f(hi));
}

// Pre-split weights: [0..65535]=hi, [65536..131071]=lo; rows = wqkv(384) ++ wproj(128).
__global__ void prep_weights(const float* __restrict__ wqkv,
                             const float* __restrict__ wproj,
                             short* __restrict__ wsp) {
    const int i = blockIdx.x * 256 + threadIdx.x;   // 0..65535
    const float f = (i < 49152) ? wqkv[i] : wproj[i - 49152];
    short hi, lo;
    split1(f, hi, lo);
    wsp[i] = hi;
    wsp[65536 + i] = lo;
}

// One block per window, 8 waves. LDS ~74.5KB -> 2 blocks/CU (16 waves/CU).
// Precision: x & weights hi/lo split; k,v,q,yn,kv single-bf16 RNE; s,z,acc fp32.
// launch_bounds(512,2): VGPR cap >=128 under either arg-2 semantics; (512,4) forced
// 64 VGPR -> scratch spills -> 130MB FETCH / 194MB WRITE (round 6 counters).
template <bool PRE>
__global__ __launch_bounds__(BLK, 2)
void sla5(const float* __restrict__ x,        // [N][128]
          const float* __restrict__ wqkv,     // [384][128]
          const float* __restrict__ wproj,    // [128][128]
          const float* __restrict__ bproj,    // [128]
          const int*   __restrict__ offsets,  // [1025]
          const short* __restrict__ wsp,      // pre-split weights (PRE)
          float*       __restrict__ out)      // [N][128]
{
    __shared__ __align__(16) short xs_hi[T * C];       // 16KB  x hi, [t][c] swz
    __shared__ __align__(16) short xs_lo[T * C];       // 16KB  x lo
    __shared__ __align__(16) short kTq[C * T];         // 16KB  p1: kT[ch][t] swz | p2: q[t][c] swz
    __shared__ __align__(16) short vTy[C * T];         // 16KB  p1: vT[ch][t] swz | p2: yn[t][c] swz
    __shared__ __align__(16) short kvs[4 * 32 * KVSTR];// 10KB  kv[h][d][c] bf16, padded rows
    __shared__ float ss[C];                            // s[h*32+c]

    const int win = blockIdx.x;
    const int beg = offsets[win];
    const int cnt = offsets[win + 1] - beg;
    if (cnt <= 0) return;
    const int nch = (cnt + T - 1) / T;

    const int tid = threadIdx.x;
    const int wv = tid >> 6, ln = tid & 63;
    const int fr = ln & 15, fg = ln >> 4;

    auto loadB = [&](int row512, int koff, bf16x8& bhi, bf16x8& blo) {
        if constexpr (PRE) {
            const int idx = row512 * C + koff;
            bhi = *(const bf16x8*)(wsp + idx);
            blo = *(const bf16x8*)(wsp + 65536 + idx);
        } else {
            const float* p = (row512 < 384) ? (wqkv + (size_t)row512 * C + koff)
                                            : (wproj + (size_t)(row512 - 384) * C + koff);
            const float4 a = *(const float4*)p;
            const float4 b = *(const float4*)(p + 4);
            const float f[8] = {a.x, a.y, a.z, a.w, b.x, b.y, b.z, b.w};
#pragma unroll
            for (int u = 0; u < 8; ++u) { short h_, l_; split1(f[u], h_, l_); bhi[u] = h_; blo[u] = l_; }
        }
    };

    auto stage = [&](int t0, int tc) {
#pragma unroll
        for (int it = 0; it < 2; ++it) {
            const int i = tid + it * BLK;          // < 1024
            const int t = i >> 4, c8 = (i & 15) << 3;
            float4 a = {0.f, 0.f, 0.f, 0.f}, b = {0.f, 0.f, 0.f, 0.f};
            if (t < tc) {
                const float* p = x + (size_t)(beg + t0 + t) * C + c8;
                a = *(const float4*)p;
                b = *(const float4*)(p + 4);
            }
            const float f[8] = {a.x, a.y, a.z, a.w, b.x, b.y, b.z, b.w};
            bf16x8 hi, lo;
#pragma unroll
            for (int u = 0; u < 8; ++u) { short h_, l_; split1(f[u], h_, l_); hi[u] = h_; lo[u] = l_; }
            const int s = t * C + (c8 ^ ((t & 7) << 3));
            *(bf16x8*)(xs_hi + s) = hi;
            *(bf16x8*)(xs_lo + s) = lo;
        }
    };

    // persistent accumulators (KV phase): wave (aH=wv>>1 head, tw=wv&1 c-tile)
    const int aH = wv >> 1, tw = wv & 1;
    f32x4 kvacc[2] = {{0.f,0.f,0.f,0.f},{0.f,0.f,0.f,0.f}};
    f32x4 sacc = {0.f, 0.f, 0.f, 0.f};
    bf16x8 ones;
#pragma unroll
    for (int u = 0; u < 8; ++u) ones[u] = (short)0x3F80;

    // =================== PASS 1: {stage | G1 k,v | KV+s} per chunk ===================
    for (int c0 = 0; c0 < nch; ++c0) {
        const int t0 = c0 * T;
        const int tc = (cnt - t0 < T) ? (cnt - t0) : T;
        stage(t0, tc);
        __syncthreads();

        {   // G1: wave -> ntiles {2wv, 2wv+1} of 16 [k(0..7) v(8..15)], all 4 m-tiles
            f32x4 acc[2][4];
#pragma unroll
            for (int ni = 0; ni < 2; ++ni)
#pragma unroll
                for (int m = 0; m < 4; ++m) acc[ni][m] = f32x4{0.f, 0.f, 0.f, 0.f};
#pragma unroll
            for (int ksi = 0; ksi < 4; ++ksi) {
                const int koff = ksi * 32 + fg * 8;
                bf16x8 ahi[4], alo[4];
#pragma unroll
                for (int m = 0; m < 4; ++m) {
                    const int row = m * 16 + fr;
                    const int s = row * C + (koff ^ ((row & 7) << 3));
                    ahi[m] = *(const bf16x8*)(xs_hi + s);
                    alo[m] = *(const bf16x8*)(xs_lo + s);
                }
#pragma unroll
                for (int ni = 0; ni < 2; ++ni) {
                    bf16x8 bhi, blo;
                    loadB(128 + (2 * wv + ni) * 16 + fr, koff, bhi, blo);
#pragma unroll
                    for (int m = 0; m < 4; ++m) {
                        acc[ni][m] = __builtin_amdgcn_mfma_f32_16x16x32_bf16(ahi[m], bhi, acc[ni][m], 0, 0, 0);
                        acc[ni][m] = __builtin_amdgcn_mfma_f32_16x16x32_bf16(ahi[m], blo, acc[ni][m], 0, 0, 0);
                        acc[ni][m] = __builtin_amdgcn_mfma_f32_16x16x32_bf16(alo[m], bhi, acc[ni][m], 0, 0, 0);
                    }
                }
            }
            // epilogue: relu(k) -> kT[ch][t]; v -> vT[ch][t]; b64-packed, swz on t-granule
#pragma unroll
            for (int ni = 0; ni < 2; ++ni) {
                const int nt = 2 * wv + ni;
                const bool isk = (nt < 8);
                const int ch = (isk ? nt : nt - 8) * 16 + fr;
                short* dst = isk ? kTq : vTy;
#pragma unroll
                for (int m = 0; m < 4; ++m) {
                    sh4 h4;
#pragma unroll
                    for (int e = 0; e < 4; ++e) {
                        float v = acc[ni][m][e];
                        if (isk) v = fmaxf(v, 0.f);
                        h4[e] = bf16rne(v);
                    }
                    const int tb = m * 16 + fg * 4;
                    *(sh4*)(dst + ch * T + (tb ^ ((ch & 7) << 3))) = h4;
                }
            }
        }
        __syncthreads();

        {   // KV: kv[aH][c][d] += kT^T v (K=64); s via ones-column MFMA
#pragma unroll
            for (int kt = 0; kt < 2; ++kt) {
                const int t8 = kt * 32 + fg * 8;
                const int cch = aH * 32 + tw * 16 + fr;
                const bf16x8 a8 = *(const bf16x8*)(kTq + cch * T + (t8 ^ ((cch & 7) << 3)));
                sacc = __builtin_amdgcn_mfma_f32_16x16x32_bf16(a8, ones, sacc, 0, 0, 0);
#pragma unroll
                for (int dt = 0; dt < 2; ++dt) {
                    const int dch = aH * 32 + dt * 16 + fr;
                    const bf16x8 b8 = *(const bf16x8*)(vTy + dch * T + (t8 ^ ((dch & 7) << 3)));
                    kvacc[dt] = __builtin_amdgcn_mfma_f32_16x16x32_bf16(a8, b8, kvacc[dt], 0, 0, 0);
                }
            }
        }
        if (c0 + 1 < nch) __syncthreads();
    }

    // KV epilogue: kv(acc D[m=c][n=d]) -> kvs[h][d][c] bf16; s -> ss
    {
#pragma unroll
        for (int dt = 0; dt < 2; ++dt) {
            const int d = dt * 16 + fr;
#pragma unroll
            for (int e = 0; e < 4; ++e) {
                const int c = tw * 16 + fg * 4 + e;
                kvs[aH * (32 * KVSTR) + d * KVSTR + c] = bf16rne(kvacc[dt][e]);
            }
        }
        if (fr == 0) {
#pragma unroll
            for (int e = 0; e < 4; ++e)
                ss[aH * 32 + tw * 16 + fg * 4 + e] = sacc[e];
        }
    }

    // =================== PASS 2: {stage? | Q | Y(z in-wave) | PROJ} per chunk ===================
    for (int c0 = 0; c0 < nch; ++c0) {
        const int t0 = c0 * T;
        const int tc = (cnt - t0 < T) ? (cnt - t0) : T;
        if (nch > 1) stage(t0, tc);     // nch==1: xs from pass1 still valid
        __syncthreads();                // also publishes kvs/ss on first iteration

        {   // Q: wave -> ntile wv; q rows 0..127
            f32x4 acc[4];
#pragma unroll
            for (int m = 0; m < 4; ++m) acc[m] = f32x4{0.f, 0.f, 0.f, 0.f};
#pragma unroll
            for (int ksi = 0; ksi < 4; ++ksi) {
                const int koff = ksi * 32 + fg * 8;
                bf16x8 ahi[4], alo[4];
#pragma unroll
                for (int m = 0; m < 4; ++m) {
                    const int row = m * 16 + fr;
                    const int s = row * C + (koff ^ ((row & 7) << 3));
                    ahi[m] = *(const bf16x8*)(xs_hi + s);
                    alo[m] = *(const bf16x8*)(xs_lo + s);
                }
                bf16x8 bhi, blo;
                loadB(wv * 16 + fr, koff, bhi, blo);
#pragma unroll
                for (int m = 0; m < 4; ++m) {
                    acc[m] = __builtin_amdgcn_mfma_f32_16x16x32_bf16(ahi[m], bhi, acc[m], 0, 0, 0);
                    acc[m] = __builtin_amdgcn_mfma_f32_16x16x32_bf16(ahi[m], blo, acc[m], 0, 0, 0);
                    acc[m] = __builtin_amdgcn_mfma_f32_16x16x32_bf16(alo[m], bhi, acc[m], 0, 0, 0);
                }
            }
            const int ch = wv * 16 + fr;
#pragma unroll
            for (int m = 0; m < 4; ++m)
#pragma unroll
                for (int e = 0; e < 4; ++e) {
                    const int t = m * 16 + fg * 4 + e;
                    kTq[t * C + (ch ^ ((t & 7) << 3))] = bf16rne(fmaxf(acc[m][e], 0.f));
                }
        }
        __syncthreads();

        {   // Y: wave (a = wv>>1 head, mp = wv&1 t-half); z computed in-wave, shfl-broadcast
            const int a = wv >> 1, mp = wv & 1;
            bf16x8 bfr[2];
#pragma unroll
            for (int dl = 0; dl < 2; ++dl)
                bfr[dl] = *(const bf16x8*)(kvs + a * (32 * KVSTR) + (dl * 16 + fr) * KVSTR + fg * 8);

            const float4 s0 = *(const float4*)(ss + a * 32 + fg * 8);
            const float4 s1 = *(const float4*)(ss + a * 32 + fg * 8 + 4);

            bf16x8 afr[2];
            float zinv[2];
#pragma unroll
            for (int mi = 0; mi < 2; ++mi) {
                const int row = (mp * 2 + mi) * 16 + fr;
                const int s = row * C + ((a * 32 + fg * 8) ^ ((row & 7) << 3));
                afr[mi] = *(const bf16x8*)(kTq + s);
                float zp = 0.f;
                zp = fmaf(bf16f(afr[mi][0]), s0.x, zp);
                zp = fmaf(bf16f(afr[mi][1]), s0.y, zp);
                zp = fmaf(bf16f(afr[mi][2]), s0.z, zp);
                zp = fmaf(bf16f(afr[mi][3]), s0.w, zp);
                zp = fmaf(bf16f(afr[mi][4]), s1.x, zp);
                zp = fmaf(bf16f(afr[mi][5]), s1.y, zp);
                zp = fmaf(bf16f(afr[mi][6]), s1.z, zp);
                zp = fmaf(bf16f(afr[mi][7]), s1.w, zp);
                zp += __shfl_xor(zp, 16);     // reduce over fg bit0
                zp += __shfl_xor(zp, 32);     // reduce over fg bit1
                zinv[mi] = 1.f / (zp + 1e-6f);   // all lanes: zinv for (head a, row fr)
            }
            f32x4 acc[2][2];
#pragma unroll
            for (int mi = 0; mi < 2; ++mi)
#pragma unroll
                for (int dl = 0; dl < 2; ++dl) {
                    acc[mi][dl] = f32x4{0.f, 0.f, 0.f, 0.f};
                    acc[mi][dl] = __builtin_amdgcn_mfma_f32_16x16x32_bf16(afr[mi], bfr[dl], acc[mi][dl], 0, 0, 0);
                }
            // epilogue: yn = y * zinv(row fg*4+e via shfl) -> vTy [t][c] swz
#pragma unroll
            for (int mi = 0; mi < 2; ++mi)
#pragma unroll
                for (int e = 0; e < 4; ++e) {
                    const float zt = __shfl(zinv[mi], fg * 4 + e);
                    const int t = (mp * 2 + mi) * 16 + fg * 4 + e;
#pragma unroll
                    for (int dl = 0; dl < 2; ++dl) {
                        const int ch = a * 32 + dl * 16 + fr;
                        vTy[t * C + (ch ^ ((t & 7) << 3))] = bf16rne(acc[mi][dl][e] * zt);
                    }
                }
        }
        __syncthreads();

        {   // PROJ: wave -> ntile wv; A = yn single bf16, B = wproj hi/lo
            f32x4 acc[4];
#pragma unroll
            for (int m = 0; m < 4; ++m) acc[m] = f32x4{0.f, 0.f, 0.f, 0.f};
#pragma unroll
            for (int ksi = 0; ksi < 4; ++ksi) {
                const int koff = ksi * 32 + fg * 8;
                bf16x8 a8[4];
#pragma unroll
                for (int m = 0; m < 4; ++m) {
                    const int row = m * 16 + fr;
                    a8[m] = *(const bf16x8*)(vTy + row * C + (koff ^ ((row & 7) << 3)));
                }
                bf16x8 bhi, blo;
                loadB(384 + wv * 16 + fr, koff, bhi, blo);
#pragma unroll
                for (int m = 0; m < 4; ++m) {
                    acc[m] = __builtin_amdgcn_mfma_f32_16x16x32_bf16(a8[m], bhi, acc[m], 0, 0, 0);
                    acc[m] = __builtin_amdgcn_mfma_f32_16x16x32_bf16(a8[m], blo, acc[m], 0, 0, 0);
                }
            }
            const int ch = wv * 16 + fr;
            const float b = bproj[ch];
#pragma unroll
            for (int m = 0; m < 4; ++m)
#pragma unroll
                for (int e = 0; e < 4; ++e) {
                    const int t = m * 16 + fg * 4 + e;
                    if (t < tc)
                        out[(size_t)(beg + t0 + t) * C + ch] = acc[m][e] + b;
                }
        }
        if (c0 + 1 < nch) __syncthreads();
    }
}

extern "C" void kernel_launch(void* const* d_in, const int* in_sizes, int n_in,
                              void* d_out, int out_size, void* d_ws, size_t ws_size,
                              hipStream_t stream)
{
    const float* x       = (const float*)d_in[0];
    const float* wqkv    = (const float*)d_in[1];
    const float* wproj   = (const float*)d_in[2];
    const float* bproj   = (const float*)d_in[3];
    const int*   offsets = (const int*)d_in[5];
    float* out = (float*)d_out;
    short* wsp = (short*)d_ws;

    const bool pre = (ws_size >= 131072u * sizeof(short));
    if (pre) {
        hipLaunchKernelGGL(prep_weights, dim3(256), dim3(256), 0, stream, wqkv, wproj, wsp);
        hipLaunchKernelGGL((sla5<true>), dim3(NWIN), dim3(BLK), 0, stream,
                           x, wqkv, wproj, bproj, offsets, wsp, out);
    } else {
        hipLaunchKernelGGL((sla5<false>), dim3(NWIN), dim3(BLK), 0, stream,
                           x, wqkv, wproj, bproj, offsets, wsp, out);
    }
}

// Round 8
// 96.134 us; speedup vs baseline: 4.2199x; 1.0536x over previous
//
#include <hip/hip_runtime.h>

namespace {
constexpr int C     = 128;
constexpr int T     = 64;    // token chunk
constexpr int BLK   = 512;   // 8 waves
constexpr int NWIN  = 1024;
constexpr int KVSTR = 40;    // kvs row stride (elems): 16B-aligned rows, ~2-way banks
constexpr int WSPN  = 131072;            // shorts for pre-split weights
constexpr size_t QWS_SHORTS = (size_t)65536 * 128;  // q scratch [N][C] bf16
}

typedef __attribute__((ext_vector_type(8))) short bf16x8;
typedef __attribute__((ext_vector_type(4))) short sh4;
typedef __attribute__((ext_vector_type(4))) float f32x4;

__device__ __forceinline__ short bf16rne(float f) {
    unsigned u = __float_as_uint(f);
    u += 0x7fffu + ((u >> 16) & 1u);
    return (short)(u >> 16);
}
__device__ __forceinline__ float bf16f(short h) {
    return __uint_as_float(((unsigned)(unsigned short)h) << 16);
}
__device__ __forceinline__ void split1(float f, short& hi, short& lo) {
    hi = bf16rne(f);
    lo = bf16rne(f - bf16f(hi));
}

// Pre-split weights: [0..65535]=hi, [65536..131071]=lo; rows = wqkv(384) ++ wproj(128).
__global__ void prep_weights(const float* __restrict__ wqkv,
                             const float* __restrict__ wproj,
                             short* __restrict__ wsp) {
    const int i = blockIdx.x * 256 + threadIdx.x;   // 0..65535
    const float f = (i < 49152) ? wqkv[i] : wproj[i - 49152];
    short hi, lo;
    split1(f, hi, lo);
    wsp[i] = hi;
    wsp[65536 + i] = lo;
}

// ============================================================================
// sla6: q computed in pass 1, stored to xs_hi (nch==1) or global qws (nch>1).
// Pass 2 has NO staging and NO Q-GEMM: chain = Y -> sync -> PROJ per chunk.
// ============================================================================
__global__ __launch_bounds__(BLK, 2)
void sla6(const float* __restrict__ x,        // [N][128]
          const float* __restrict__ bproj,    // [128]
          const int*   __restrict__ offsets,  // [1025]
          const short* __restrict__ wsp,      // pre-split weights
          short*       __restrict__ qws,      // q scratch [N][128] bf16
          float*       __restrict__ out)      // [N][128]
{
    __shared__ __align__(16) short xs_hi[T * C];       // 16KB  x hi (p1) | q [t][c] swz (p2, nch==1)
    __shared__ __align__(16) short xs_lo[T * C];       // 16KB  x lo
    __shared__ __align__(16) short kT[C * T];          // 16KB  kT[ch][t] swz (p1 only)
    __shared__ __align__(16) short vTy[C * T];         // 16KB  p1: vT[ch][t] swz | p2: yn[t][c] swz
    __shared__ __align__(16) short kvs[4 * 32 * KVSTR];// 10KB  kv[h][d][c] bf16, padded rows
    __shared__ float ss[C];                            // s[h*32+c]

    const int win = blockIdx.x;
    const int beg = offsets[win];
    const int cnt = offsets[win + 1] - beg;
    if (cnt <= 0) return;
    const int nch = (cnt + T - 1) / T;

    const int tid = threadIdx.x;
    const int wv = tid >> 6, ln = tid & 63;
    const int fr = ln & 15, fg = ln >> 4;

    auto loadB = [&](int row512, int koff, bf16x8& bhi, bf16x8& blo) {
        const int idx = row512 * C + koff;
        bhi = *(const bf16x8*)(wsp + idx);
        blo = *(const bf16x8*)(wsp + 65536 + idx);
    };

    auto stage = [&](int t0, int tc) {
#pragma unroll
        for (int it = 0; it < 2; ++it) {
            const int i = tid + it * BLK;          // < 1024
            const int t = i >> 4, c8 = (i & 15) << 3;
            float4 a = {0.f, 0.f, 0.f, 0.f}, b = {0.f, 0.f, 0.f, 0.f};
            if (t < tc) {
                const float* p = x + (size_t)(beg + t0 + t) * C + c8;
                a = *(const float4*)p;
                b = *(const float4*)(p + 4);
            }
            const float f[8] = {a.x, a.y, a.z, a.w, b.x, b.y, b.z, b.w};
            bf16x8 hi, lo;
#pragma unroll
            for (int u = 0; u < 8; ++u) { short h_, l_; split1(f[u], h_, l_); hi[u] = h_; lo[u] = l_; }
            const int s = t * C + (c8 ^ ((t & 7) << 3));
            *(bf16x8*)(xs_hi + s) = hi;
            *(bf16x8*)(xs_lo + s) = lo;
        }
    };

    // persistent accumulators (KV phase): wave (aH=wv>>1 head, tw=wv&1 c-tile)
    const int aH = wv >> 1, tw = wv & 1;
    f32x4 kvacc[2] = {{0.f,0.f,0.f,0.f},{0.f,0.f,0.f,0.f}};
    f32x4 sacc = {0.f, 0.f, 0.f, 0.f};
    bf16x8 ones;
#pragma unroll
    for (int u = 0; u < 8; ++u) ones[u] = (short)0x3F80;

    // =================== PASS 1: {stage | G1 q,k,v | q-store + KV+s} ===================
    for (int c0 = 0; c0 < nch; ++c0) {
        const int t0 = c0 * T;
        const int tc = (cnt - t0 < T) ? (cnt - t0) : T;
        stage(t0, tc);
        __syncthreads();

        sh4 qreg[4];
        {   // G1a: k/v — wave -> ntiles {2wv, 2wv+1} of 16 [k(0..7) v(8..15)], 4 m-tiles
            f32x4 acc[2][4];
#pragma unroll
            for (int ni = 0; ni < 2; ++ni)
#pragma unroll
                for (int m = 0; m < 4; ++m) acc[ni][m] = f32x4{0.f, 0.f, 0.f, 0.f};
#pragma unroll
            for (int ksi = 0; ksi < 4; ++ksi) {
                const int koff = ksi * 32 + fg * 8;
                bf16x8 ahi[4], alo[4];
#pragma unroll
                for (int m = 0; m < 4; ++m) {
                    const int row = m * 16 + fr;
                    const int s = row * C + (koff ^ ((row & 7) << 3));
                    ahi[m] = *(const bf16x8*)(xs_hi + s);
                    alo[m] = *(const bf16x8*)(xs_lo + s);
                }
#pragma unroll
                for (int ni = 0; ni < 2; ++ni) {
                    bf16x8 bhi, blo;
                    loadB(128 + (2 * wv + ni) * 16 + fr, koff, bhi, blo);
#pragma unroll
                    for (int m = 0; m < 4; ++m) {
                        acc[ni][m] = __builtin_amdgcn_mfma_f32_16x16x32_bf16(ahi[m], bhi, acc[ni][m], 0, 0, 0);
                        acc[ni][m] = __builtin_amdgcn_mfma_f32_16x16x32_bf16(ahi[m], blo, acc[ni][m], 0, 0, 0);
                        acc[ni][m] = __builtin_amdgcn_mfma_f32_16x16x32_bf16(alo[m], bhi, acc[ni][m], 0, 0, 0);
                    }
                }
            }
            // epilogue: relu(k) -> kT[ch][t]; v -> vT[ch][t]; b64-packed, swz on t-granule
#pragma unroll
            for (int ni = 0; ni < 2; ++ni) {
                const int nt = 2 * wv + ni;
                const bool isk = (nt < 8);
                const int ch = (isk ? nt : nt - 8) * 16 + fr;
                short* dst = isk ? kT : vTy;
#pragma unroll
                for (int m = 0; m < 4; ++m) {
                    sh4 h4;
#pragma unroll
                    for (int e = 0; e < 4; ++e) {
                        float v = acc[ni][m][e];
                        if (isk) v = fmaxf(v, 0.f);
                        h4[e] = bf16rne(v);
                    }
                    const int tb = m * 16 + fg * 4;
                    *(sh4*)(dst + ch * T + (tb ^ ((ch & 7) << 3))) = h4;
                }
            }
        }
        {   // G1b: q — wave -> ntile wv (wqkv rows 0..127); result held in qreg
            f32x4 acc[4];
#pragma unroll
            for (int m = 0; m < 4; ++m) acc[m] = f32x4{0.f, 0.f, 0.f, 0.f};
#pragma unroll
            for (int ksi = 0; ksi < 4; ++ksi) {
                const int koff = ksi * 32 + fg * 8;
                bf16x8 ahi[4], alo[4];
#pragma unroll
                for (int m = 0; m < 4; ++m) {
                    const int row = m * 16 + fr;
                    const int s = row * C + (koff ^ ((row & 7) << 3));
                    ahi[m] = *(const bf16x8*)(xs_hi + s);
                    alo[m] = *(const bf16x8*)(xs_lo + s);
                }
                bf16x8 bhi, blo;
                loadB(wv * 16 + fr, koff, bhi, blo);
#pragma unroll
                for (int m = 0; m < 4; ++m) {
                    acc[m] = __builtin_amdgcn_mfma_f32_16x16x32_bf16(ahi[m], bhi, acc[m], 0, 0, 0);
                    acc[m] = __builtin_amdgcn_mfma_f32_16x16x32_bf16(ahi[m], blo, acc[m], 0, 0, 0);
                    acc[m] = __builtin_amdgcn_mfma_f32_16x16x32_bf16(alo[m], bhi, acc[m], 0, 0, 0);
                }
            }
#pragma unroll
            for (int m = 0; m < 4; ++m)
#pragma unroll
                for (int e = 0; e < 4; ++e)
                    qreg[m][e] = bf16rne(fmaxf(acc[m][e], 0.f));
        }
        __syncthreads();   // kT/vT written -> KV read; all xs reads done -> q-store safe

        {   // q-store: nch==1 -> xs_hi [t][c] swz (pass2 source); else -> global qws
            const int ch = wv * 16 + fr;
            if (nch == 1) {
#pragma unroll
                for (int m = 0; m < 4; ++m)
#pragma unroll
                    for (int e = 0; e < 4; ++e) {
                        const int t = m * 16 + fg * 4 + e;
                        xs_hi[t * C + (ch ^ ((t & 7) << 3))] = qreg[m][e];
                    }
            } else {
#pragma unroll
                for (int m = 0; m < 4; ++m)
#pragma unroll
                    for (int e = 0; e < 4; ++e) {
                        const int t = m * 16 + fg * 4 + e;
                        if (t < tc)
                            qws[(size_t)(beg + t0 + t) * C + ch] = qreg[m][e];
                    }
            }
        }
        {   // KV: kv[aH][c][d] += kT^T v (K=64); s via ones-column MFMA
#pragma unroll
            for (int kt = 0; kt < 2; ++kt) {
                const int t8 = kt * 32 + fg * 8;
                const int cch = aH * 32 + tw * 16 + fr;
                const bf16x8 a8 = *(const bf16x8*)(kT + cch * T + (t8 ^ ((cch & 7) << 3)));
                sacc = __builtin_amdgcn_mfma_f32_16x16x32_bf16(a8, ones, sacc, 0, 0, 0);
#pragma unroll
                for (int dt = 0; dt < 2; ++dt) {
                    const int dch = aH * 32 + dt * 16 + fr;
                    const bf16x8 b8 = *(const bf16x8*)(vTy + dch * T + (t8 ^ ((dch & 7) << 3)));
                    kvacc[dt] = __builtin_amdgcn_mfma_f32_16x16x32_bf16(a8, b8, kvacc[dt], 0, 0, 0);
                }
            }
        }
        if (c0 + 1 < nch) __syncthreads();
    }

    // KV epilogue: kv(acc D[m=c][n=d]) -> kvs[h][d][c] bf16; s -> ss
    {
#pragma unroll
        for (int dt = 0; dt < 2; ++dt) {
            const int d = dt * 16 + fr;
#pragma unroll
            for (int e = 0; e < 4; ++e) {
                const int c = tw * 16 + fg * 4 + e;
                kvs[aH * (32 * KVSTR) + d * KVSTR + c] = bf16rne(kvacc[dt][e]);
            }
        }
        if (fr == 0) {
#pragma unroll
            for (int e = 0; e < 4; ++e)
                ss[aH * 32 + tw * 16 + fg * 4 + e] = sacc[e];
        }
    }
    __syncthreads();   // kvs/ss (and q->xs_hi) visible

    // =================== PASS 2: {Y (z in-wave) | PROJ} per chunk — no staging ===============
    for (int c0 = 0; c0 < nch; ++c0) {
        const int t0 = c0 * T;
        const int tc = (cnt - t0 < T) ? (cnt - t0) : T;

        {   // Y: wave (a = wv>>1 head, mp = wv&1 t-half)
            const int a = wv >> 1, mp = wv & 1;
            bf16x8 bfr[2];
#pragma unroll
            for (int dl = 0; dl < 2; ++dl)
                bfr[dl] = *(const bf16x8*)(kvs + a * (32 * KVSTR) + (dl * 16 + fr) * KVSTR + fg * 8);

            const float4 s0 = *(const float4*)(ss + a * 32 + fg * 8);
            const float4 s1 = *(const float4*)(ss + a * 32 + fg * 8 + 4);

            bf16x8 afr[2];
            float zinv[2];
#pragma unroll
            for (int mi = 0; mi < 2; ++mi) {
                const int row = (mp * 2 + mi) * 16 + fr;
                if (nch == 1) {
                    afr[mi] = *(const bf16x8*)(xs_hi + row * C + ((a * 32 + fg * 8) ^ ((row & 7) << 3)));
                } else {
                    afr[mi] = *(const bf16x8*)(qws + (size_t)(beg + t0 + row) * C + a * 32 + fg * 8);
                }
                float zp = 0.f;
                zp = fmaf(bf16f(afr[mi][0]), s0.x, zp);
                zp = fmaf(bf16f(afr[mi][1]), s0.y, zp);
                zp = fmaf(bf16f(afr[mi][2]), s0.z, zp);
                zp = fmaf(bf16f(afr[mi][3]), s0.w, zp);
                zp = fmaf(bf16f(afr[mi][4]), s1.x, zp);
                zp = fmaf(bf16f(afr[mi][5]), s1.y, zp);
                zp = fmaf(bf16f(afr[mi][6]), s1.z, zp);
                zp = fmaf(bf16f(afr[mi][7]), s1.w, zp);
                zp += __shfl_xor(zp, 16);
                zp += __shfl_xor(zp, 32);
                zinv[mi] = 1.f / (zp + 1e-6f);
            }
            f32x4 acc[2][2];
#pragma unroll
            for (int mi = 0; mi < 2; ++mi)
#pragma unroll
                for (int dl = 0; dl < 2; ++dl) {
                    acc[mi][dl] = f32x4{0.f, 0.f, 0.f, 0.f};
                    acc[mi][dl] = __builtin_amdgcn_mfma_f32_16x16x32_bf16(afr[mi], bfr[dl], acc[mi][dl], 0, 0, 0);
                }
#pragma unroll
            for (int mi = 0; mi < 2; ++mi)
#pragma unroll
                for (int e = 0; e < 4; ++e) {
                    const float zt = __shfl(zinv[mi], fg * 4 + e);
                    const int t = (mp * 2 + mi) * 16 + fg * 4 + e;
#pragma unroll
                    for (int dl = 0; dl < 2; ++dl) {
                        const int ch = a * 32 + dl * 16 + fr;
                        vTy[t * C + (ch ^ ((t & 7) << 3))] = bf16rne(acc[mi][dl][e] * zt);
                    }
                }
        }
        __syncthreads();

        {   // PROJ: wave -> ntile wv; A = yn single bf16, B = wproj hi/lo
            f32x4 acc[4];
#pragma unroll
            for (int m = 0; m < 4; ++m) acc[m] = f32x4{0.f, 0.f, 0.f, 0.f};
#pragma unroll
            for (int ksi = 0; ksi < 4; ++ksi) {
                const int koff = ksi * 32 + fg * 8;
                bf16x8 a8[4];
#pragma unroll
                for (int m = 0; m < 4; ++m) {
                    const int row = m * 16 + fr;
                    a8[m] = *(const bf16x8*)(vTy + row * C + (koff ^ ((row & 7) << 3)));
                }
                bf16x8 bhi, blo;
                loadB(384 + wv * 16 + fr, koff, bhi, blo);
#pragma unroll
                for (int m = 0; m < 4; ++m) {
                    acc[m] = __builtin_amdgcn_mfma_f32_16x16x32_bf16(a8[m], bhi, acc[m], 0, 0, 0);
                    acc[m] = __builtin_amdgcn_mfma_f32_16x16x32_bf16(a8[m], blo, acc[m], 0, 0, 0);
                }
            }
            const int ch = wv * 16 + fr;
            const float b = bproj[ch];
#pragma unroll
            for (int m = 0; m < 4; ++m)
#pragma unroll
                for (int e = 0; e < 4; ++e) {
                    const int t = m * 16 + fg * 4 + e;
                    if (t < tc)
                        out[(size_t)(beg + t0 + t) * C + ch] = acc[m][e] + b;
                }
        }
        if (c0 + 1 < nch) __syncthreads();
    }
}

// ============================================================================
// sla5: round-7 fused kernel, kept as fallback when ws is too small for qws.
// ============================================================================
template <bool PRE>
__global__ __launch_bounds__(BLK, 2)
void sla5(const float* __restrict__ x, const float* __restrict__ wqkv,
          const float* __restrict__ wproj, const float* __restrict__ bproj,
          const int* __restrict__ offsets, const short* __restrict__ wsp,
          float* __restrict__ out)
{
    __shared__ __align__(16) short xs_hi[T * C];
    __shared__ __align__(16) short xs_lo[T * C];
    __shared__ __align__(16) short kTq[C * T];
    __shared__ __align__(16) short vTy[C * T];
    __shared__ __align__(16) short kvs[4 * 32 * KVSTR];
    __shared__ float ss[C];

    const int win = blockIdx.x;
    const int beg = offsets[win];
    const int cnt = offsets[win + 1] - beg;
    if (cnt <= 0) return;
    const int nch = (cnt + T - 1) / T;

    const int tid = threadIdx.x;
    const int wv = tid >> 6, ln = tid & 63;
    const int fr = ln & 15, fg = ln >> 4;

    auto loadB = [&](int row512, int koff, bf16x8& bhi, bf16x8& blo) {
        if constexpr (PRE) {
            const int idx = row512 * C + koff;
            bhi = *(const bf16x8*)(wsp + idx);
            blo = *(const bf16x8*)(wsp + 65536 + idx);
        } else {
            const float* p = (row512 < 384) ? (wqkv + (size_t)row512 * C + koff)
                                            : (wproj + (size_t)(row512 - 384) * C + koff);
            const float4 a = *(const float4*)p;
            const float4 b = *(const float4*)(p + 4);
            const float f[8] = {a.x, a.y, a.z, a.w, b.x, b.y, b.z, b.w};
#pragma unroll
            for (int u = 0; u < 8; ++u) { short h_, l_; split1(f[u], h_, l_); bhi[u] = h_; blo[u] = l_; }
        }
    };

    auto stage = [&](int t0, int tc) {
#pragma unroll
        for (int it = 0; it < 2; ++it) {
            const int i = tid + it * BLK;
            const int t = i >> 4, c8 = (i & 15) << 3;
            float4 a = {0.f, 0.f, 0.f, 0.f}, b = {0.f, 0.f, 0.f, 0.f};
            if (t < tc) {
                const float* p = x + (size_t)(beg + t0 + t) * C + c8;
                a = *(const float4*)p;
                b = *(const float4*)(p + 4);
            }
            const float f[8] = {a.x, a.y, a.z, a.w, b.x, b.y, b.z, b.w};
            bf16x8 hi, lo;
#pragma unroll
            for (int u = 0; u < 8; ++u) { short h_, l_; split1(f[u], h_, l_); hi[u] = h_; lo[u] = l_; }
            const int s = t * C + (c8 ^ ((t & 7) << 3));
            *(bf16x8*)(xs_hi + s) = hi;
            *(bf16x8*)(xs_lo + s) = lo;
        }
    };

    const int aH = wv >> 1, tw = wv & 1;
    f32x4 kvacc[2] = {{0.f,0.f,0.f,0.f},{0.f,0.f,0.f,0.f}};
    f32x4 sacc = {0.f, 0.f, 0.f, 0.f};
    bf16x8 ones;
#pragma unroll
    for (int u = 0; u < 8; ++u) ones[u] = (short)0x3F80;

    for (int c0 = 0; c0 < nch; ++c0) {
        const int t0 = c0 * T;
        const int tc = (cnt - t0 < T) ? (cnt - t0) : T;
        stage(t0, tc);
        __syncthreads();
        {
            f32x4 acc[2][4];
#pragma unroll
            for (int ni = 0; ni < 2; ++ni)
#pragma unroll
                for (int m = 0; m < 4; ++m) acc[ni][m] = f32x4{0.f, 0.f, 0.f, 0.f};
#pragma unroll
            for (int ksi = 0; ksi < 4; ++ksi) {
                const int koff = ksi * 32 + fg * 8;
                bf16x8 ahi[4], alo[4];
#pragma unroll
                for (int m = 0; m < 4; ++m) {
                    const int row = m * 16 + fr;
                    const int s = row * C + (koff ^ ((row & 7) << 3));
                    ahi[m] = *(const bf16x8*)(xs_hi + s);
                    alo[m] = *(const bf16x8*)(xs_lo + s);
                }
#pragma unroll
                for (int ni = 0; ni < 2; ++ni) {
                    bf16x8 bhi, blo;
                    loadB(128 + (2 * wv + ni) * 16 + fr, koff, bhi, blo);
#pragma unroll
                    for (int m = 0; m < 4; ++m) {
                        acc[ni][m] = __builtin_amdgcn_mfma_f32_16x16x32_bf16(ahi[m], bhi, acc[ni][m], 0, 0, 0);
                        acc[ni][m] = __builtin_amdgcn_mfma_f32_16x16x32_bf16(ahi[m], blo, acc[ni][m], 0, 0, 0);
                        acc[ni][m] = __builtin_amdgcn_mfma_f32_16x16x32_bf16(alo[m], bhi, acc[ni][m], 0, 0, 0);
                    }
                }
            }
#pragma unroll
            for (int ni = 0; ni < 2; ++ni) {
                const int nt = 2 * wv + ni;
                const bool isk = (nt < 8);
                const int ch = (isk ? nt : nt - 8) * 16 + fr;
                short* dst = isk ? kTq : vTy;
#pragma unroll
                for (int m = 0; m < 4; ++m) {
                    sh4 h4;
#pragma unroll
                    for (int e = 0; e < 4; ++e) {
                        float v = acc[ni][m][e];
                        if (isk) v = fmaxf(v, 0.f);
                        h4[e] = bf16rne(v);
                    }
                    const int tb = m * 16 + fg * 4;
                    *(sh4*)(dst + ch * T + (tb ^ ((ch & 7) << 3))) = h4;
                }
            }
        }
        __syncthreads();
        {
#pragma unroll
            for (int kt = 0; kt < 2; ++kt) {
                const int t8 = kt * 32 + fg * 8;
                const int cch = aH * 32 + tw * 16 + fr;
                const bf16x8 a8 = *(const bf16x8*)(kTq + cch * T + (t8 ^ ((cch & 7) << 3)));
                sacc = __builtin_amdgcn_mfma_f32_16x16x32_bf16(a8, ones, sacc, 0, 0, 0);
#pragma unroll
                for (int dt = 0; dt < 2; ++dt) {
                    const int dch = aH * 32 + dt * 16 + fr;
                    const bf16x8 b8 = *(const bf16x8*)(vTy + dch * T + (t8 ^ ((dch & 7) << 3)));
                    kvacc[dt] = __builtin_amdgcn_mfma_f32_16x16x32_bf16(a8, b8, kvacc[dt], 0, 0, 0);
                }
            }
        }
        if (c0 + 1 < nch) __syncthreads();
    }
    {
#pragma unroll
        for (int dt = 0; dt < 2; ++dt) {
            const int d = dt * 16 + fr;
#pragma unroll
            for (int e = 0; e < 4; ++e) {
                const int c = tw * 16 + fg * 4 + e;
                kvs[aH * (32 * KVSTR) + d * KVSTR + c] = bf16rne(kvacc[dt][e]);
            }
        }
        if (fr == 0) {
#pragma unroll
            for (int e = 0; e < 4; ++e)
                ss[aH * 32 + tw * 16 + fg * 4 + e] = sacc[e];
        }
    }
    for (int c0 = 0; c0 < nch; ++c0) {
        const int t0 = c0 * T;
        const int tc = (cnt - t0 < T) ? (cnt - t0) : T;
        if (nch > 1) stage(t0, tc);
        __syncthreads();
        {
            f32x4 acc[4];
#pragma unroll
            for (int m = 0; m < 4; ++m) acc[m] = f32x4{0.f, 0.f, 0.f, 0.f};
#pragma unroll
            for (int ksi = 0; ksi < 4; ++ksi) {
                const int koff = ksi * 32 + fg * 8;
                bf16x8 ahi[4], alo[4];
#pragma unroll
                for (int m = 0; m < 4; ++m) {
                    const int row = m * 16 + fr;
                    const int s = row * C + (koff ^ ((row & 7) << 3));
                    ahi[m] = *(const bf16x8*)(xs_hi + s);
                    alo[m] = *(const bf16x8*)(xs_lo + s);
                }
                bf16x8 bhi, blo;
                loadB(wv * 16 + fr, koff, bhi, blo);
#pragma unroll
                for (int m = 0; m < 4; ++m) {
                    acc[m] = __builtin_amdgcn_mfma_f32_16x16x32_bf16(ahi[m], bhi, acc[m], 0, 0, 0);
                    acc[m] = __builtin_amdgcn_mfma_f32_16x16x32_bf16(ahi[m], blo, acc[m], 0, 0, 0);
                    acc[m] = __builtin_amdgcn_mfma_f32_16x16x32_bf16(alo[m], bhi, acc[m], 0, 0, 0);
                }
            }
            const int ch = wv * 16 + fr;
#pragma unroll
            for (int m = 0; m < 4; ++m)
#pragma unroll
                for (int e = 0; e < 4; ++e) {
                    const int t = m * 16 + fg * 4 + e;
                    kTq[t * C + (ch ^ ((t & 7) << 3))] = bf16rne(fmaxf(acc[m][e], 0.f));
                }
        }
        __syncthreads();
        {
            const int a = wv >> 1, mp = wv & 1;
            bf16x8 bfr[2];
#pragma unroll
            for (int dl = 0; dl < 2; ++dl)
                bfr[dl] = *(const bf16x8*)(kvs + a * (32 * KVSTR) + (dl * 16 + fr) * KVSTR + fg * 8);
            const float4 s0 = *(const float4*)(ss + a * 32 + fg * 8);
            const float4 s1 = *(const float4*)(ss + a * 32 + fg * 8 + 4);
            bf16x8 afr[2];
            float zinv[2];
#pragma unroll
            for (int mi = 0; mi < 2; ++mi) {
                const int row = (mp * 2 + mi) * 16 + fr;
                const int s = row * C + ((a * 32 + fg * 8) ^ ((row & 7) << 3));
                afr[mi] = *(const bf16x8*)(kTq + s);
                float zp = 0.f;
                zp = fmaf(bf16f(afr[mi][0]), s0.x, zp);
                zp = fmaf(bf16f(afr[mi][1]), s0.y, zp);
                zp = fmaf(bf16f(afr[mi][2]), s0.z, zp);
                zp = fmaf(bf16f(afr[mi][3]), s0.w, zp);
                zp = fmaf(bf16f(afr[mi][4]), s1.x, zp);
                zp = fmaf(bf16f(afr[mi][5]), s1.y, zp);
                zp = fmaf(bf16f(afr[mi][6]), s1.z, zp);
                zp = fmaf(bf16f(afr[mi][7]), s1.w, zp);
                zp += __shfl_xor(zp, 16);
                zp += __shfl_xor(zp, 32);
                zinv[mi] = 1.f / (zp + 1e-6f);
            }
            f32x4 acc[2][2];
#pragma unroll
            for (int mi = 0; mi < 2; ++mi)
#pragma unroll
                for (int dl = 0; dl < 2; ++dl) {
                    acc[mi][dl] = f32x4{0.f, 0.f, 0.f, 0.f};
                    acc[mi][dl] = __builtin_amdgcn_mfma_f32_16x16x32_bf16(afr[mi], bfr[dl], acc[mi][dl], 0, 0, 0);
                }
#pragma unroll
            for (int mi = 0; mi < 2; ++mi)
#pragma unroll
                for (int e = 0; e < 4; ++e) {
                    const float zt = __shfl(zinv[mi], fg * 4 + e);
                    const int t = (mp * 2 + mi) * 16 + fg * 4 + e;
#pragma unroll
                    for (int dl = 0; dl < 2; ++dl) {
                        const int ch = a * 32 + dl * 16 + fr;
                        vTy[t * C + (ch ^ ((t & 7) << 3))] = bf16rne(acc[mi][dl][e] * zt);
                    }
                }
        }
        __syncthreads();
        {
            f32x4 acc[4];
#pragma unroll
            for (int m = 0; m < 4; ++m) acc[m] = f32x4{0.f, 0.f, 0.f, 0.f};
#pragma unroll
            for (int ksi = 0; ksi < 4; ++ksi) {
                const int koff = ksi * 32 + fg * 8;
                bf16x8 a8[4];
#pragma unroll
                for (int m = 0; m < 4; ++m) {
                    const int row = m * 16 + fr;
                    a8[m] = *(const bf16x8*)(vTy + row * C + (koff ^ ((row & 7) << 3)));
                }
                bf16x8 bhi, blo;
                loadB(384 + wv * 16 + fr, koff, bhi, blo);
#pragma unroll
                for (int m = 0; m < 4; ++m) {
                    acc[m] = __builtin_amdgcn_mfma_f32_16x16x32_bf16(a8[m], bhi, acc[m], 0, 0, 0);
                    acc[m] = __builtin_amdgcn_mfma_f32_16x16x32_bf16(a8[m], blo, acc[m], 0, 0, 0);
                }
            }
            const int ch = wv * 16 + fr;
            const float b = bproj[ch];
#pragma unroll
            for (int m = 0; m < 4; ++m)
#pragma unroll
                for (int e = 0; e < 4; ++e) {
                    const int t = m * 16 + fg * 4 + e;
                    if (t < tc)
                        out[(size_t)(beg + t0 + t) * C + ch] = acc[m][e] + b;
                }
        }
        if (c0 + 1 < nch) __syncthreads();
    }
}

extern "C" void kernel_launch(void* const* d_in, const int* in_sizes, int n_in,
                              void* d_out, int out_size, void* d_ws, size_t ws_size,
                              hipStream_t stream)
{
    const float* x       = (const float*)d_in[0];
    const float* wqkv    = (const float*)d_in[1];
    const float* wproj   = (const float*)d_in[2];
    const float* bproj   = (const float*)d_in[3];
    const int*   offsets = (const int*)d_in[5];
    float* out = (float*)d_out;
    short* wsp = (short*)d_ws;

    const size_t need_full = (size_t)(WSPN + QWS_SHORTS) * sizeof(short);
    if (ws_size >= need_full) {
        hipLaunchKernelGGL(prep_weights, dim3(256), dim3(256), 0, stream, wqkv, wproj, wsp);
        hipLaunchKernelGGL(sla6, dim3(NWIN), dim3(BLK), 0, stream,
                           x, bproj, offsets, wsp, wsp + WSPN, out);
    } else if (ws_size >= (size_t)WSPN * sizeof(short)) {
        hipLaunchKernelGGL(prep_weights, dim3(256), dim3(256), 0, stream, wqkv, wproj, wsp);
        hipLaunchKernelGGL((sla5<true>), dim3(NWIN), dim3(BLK), 0, stream,
                           x, wqkv, wproj, bproj, offsets, wsp, out);
    } else {
        hipLaunchKernelGGL((sla5<false>), dim3(NWIN), dim3(BLK), 0, stream,
                           x, wqkv, wproj, bproj, offsets, wsp, out);
    }
}

// Round 9
// 76.291 us; speedup vs baseline: 5.3175x; 1.2601x over previous
//
#include <hip/hip_runtime.h>

namespace {
constexpr int C     = 128;
constexpr int T     = 64;    // token chunk
constexpr int BLK   = 512;   // 8 waves
constexpr int NWIN  = 1024;
constexpr int KVSTR = 40;    // kvs row stride
constexpr int KTSTR = 72;    // kT/vT row stride (pad: 16B-aligned rows, bank-spread)
constexpr int YNSTR = 136;   // yn / x-stage row stride
constexpr int WSPN  = 131072;                 // shorts for pre-split weights
constexpr size_t QN = (size_t)65536 * 128;    // shorts per q/k/v plane
}

typedef __attribute__((ext_vector_type(8))) short bf16x8;
typedef __attribute__((ext_vector_type(4))) short sh4;
typedef __attribute__((ext_vector_type(4))) float f32x4;

__device__ __forceinline__ short bf16rne(float f) {
    unsigned u = __float_as_uint(f);
    u += 0x7fffu + ((u >> 16) & 1u);
    return (short)(u >> 16);
}
__device__ __forceinline__ float bf16f(short h) {
    return __uint_as_float(((unsigned)(unsigned short)h) << 16);
}
__device__ __forceinline__ void split1(float f, short& hi, short& lo) {
    hi = bf16rne(f);
    lo = bf16rne(f - bf16f(hi));
}

// Pre-split weights: [0..65535]=hi, [65536..131071]=lo; rows = wqkv(384) ++ wproj(128).
__global__ void prep_weights(const float* __restrict__ wqkv,
                             const float* __restrict__ wproj,
                             short* __restrict__ wsp) {
    const int i = blockIdx.x * 256 + threadIdx.x;
    const float f = (i < 49152) ? wqkv[i] : wproj[i - 49152];
    short hi, lo;
    split1(f, hi, lo);
    wsp[i] = hi;
    wsp[65536 + i] = lo;
}

// ============================================================================
// K1: dense qkv GEMM. 1024 blocks x 64 rows, ONE barrier per block.
// Bitwise-identical MFMA order to sla6's G1 -> same q/k/v values.
// ============================================================================
__global__ __launch_bounds__(BLK, 2)
void qkv_gemm(const float* __restrict__ x,       // [N][128]
              const short* __restrict__ wsp,     // pre-split weights
              short* __restrict__ qws,           // [N][128] bf16 (relu)
              short* __restrict__ kws,           // [N][128] bf16 (relu)
              short* __restrict__ vws)           // [N][128] bf16
{
    __shared__ __align__(16) short xh[64 * YNSTR];   // 17.4KB, pad-136 rows
    __shared__ __align__(16) short xl[64 * YNSTR];

    const int tid = threadIdx.x;
    const int wv = tid >> 6, ln = tid & 63;
    const int fr = ln & 15, fg = ln >> 4;
    const int r0 = blockIdx.x * 64;

    // stage 64 rows of x, split hi/lo
#pragma unroll
    for (int it = 0; it < 2; ++it) {
        const int i = tid + it * BLK;              // < 1024
        const int t = i >> 4, c8 = (i & 15) << 3;
        const float* p = x + (size_t)(r0 + t) * C + c8;
        const float4 a = *(const float4*)p;
        const float4 b = *(const float4*)(p + 4);
        const float f[8] = {a.x, a.y, a.z, a.w, b.x, b.y, b.z, b.w};
        bf16x8 hi, lo;
#pragma unroll
        for (int u = 0; u < 8; ++u) { short h_, l_; split1(f[u], h_, l_); hi[u] = h_; lo[u] = l_; }
        *(bf16x8*)(xh + t * YNSTR + c8) = hi;
        *(bf16x8*)(xl + t * YNSTR + c8) = lo;
    }
    __syncthreads();

    // wave wv: n-tiles {3wv..3wv+2} of 24 (q 0..7, k 8..15, v 16..23), all 4 m-tiles
    f32x4 acc[3][4];
#pragma unroll
    for (int ni = 0; ni < 3; ++ni)
#pragma unroll
        for (int m = 0; m < 4; ++m) acc[ni][m] = f32x4{0.f, 0.f, 0.f, 0.f};

#pragma unroll
    for (int ksi = 0; ksi < 4; ++ksi) {
        const int koff = ksi * 32 + fg * 8;
        bf16x8 ahi[4], alo[4];
#pragma unroll
        for (int m = 0; m < 4; ++m) {
            const int row = m * 16 + fr;
            ahi[m] = *(const bf16x8*)(xh + row * YNSTR + koff);
            alo[m] = *(const bf16x8*)(xl + row * YNSTR + koff);
        }
#pragma unroll
        for (int ni = 0; ni < 3; ++ni) {
            const int idx = ((3 * wv + ni) * 16 + fr) * C + koff;
            const bf16x8 bhi = *(const bf16x8*)(wsp + idx);
            const bf16x8 blo = *(const bf16x8*)(wsp + 65536 + idx);
#pragma unroll
            for (int m = 0; m < 4; ++m) {
                acc[ni][m] = __builtin_amdgcn_mfma_f32_16x16x32_bf16(ahi[m], bhi, acc[ni][m], 0, 0, 0);
                acc[ni][m] = __builtin_amdgcn_mfma_f32_16x16x32_bf16(ahi[m], blo, acc[ni][m], 0, 0, 0);
                acc[ni][m] = __builtin_amdgcn_mfma_f32_16x16x32_bf16(alo[m], bhi, acc[ni][m], 0, 0, 0);
            }
        }
    }

    // store q/k/v bf16 (L2 merges the 2B scalars into full lines)
#pragma unroll
    for (int ni = 0; ni < 3; ++ni) {
        const int gch = (3 * wv + ni) * 16 + fr;     // 0..383
        short* dst = (gch < 128) ? qws : ((gch < 256) ? kws : vws);
        const int ch = gch & 127;
        const bool rl = (gch < 256);                 // relu on q and k
#pragma unroll
        for (int m = 0; m < 4; ++m)
#pragma unroll
            for (int e = 0; e < 4; ++e) {
                const int t = m * 16 + fg * 4 + e;
                float v = acc[ni][m][e];
                if (rl) v = fmaxf(v, 0.f);
                dst[(size_t)(r0 + t) * C + ch] = bf16rne(v);
            }
    }
}

// ============================================================================
// K23: per-window. stage kT/vT (transpose, no conversion) -> KV -> Y -> PROJ.
// 3 barriers per 1-chunk window.
// ============================================================================
__global__ __launch_bounds__(BLK, 2)
void sla_win(const short* __restrict__ qws,
             const short* __restrict__ kws,
             const short* __restrict__ vws,
             const short* __restrict__ wsp,
             const float* __restrict__ bproj,
             const int*   __restrict__ offsets,
             float*       __restrict__ out)
{
    __shared__ __align__(16) short kT[C * KTSTR];      // 18.4KB  kT[c][t] pad-72 + t-granule XOR
    __shared__ __align__(16) short vT[C * KTSTR];      // 18.4KB
    __shared__ __align__(16) short yn[T * YNSTR];      // 17.4KB  yn[t][c] pad-136
    __shared__ __align__(16) short kvs[4 * 32 * KVSTR];// 10.2KB  kv[h][d][c]
    __shared__ float ss[C];

    const int win = blockIdx.x;
    const int beg = offsets[win];
    const int cnt = offsets[win + 1] - beg;
    if (cnt <= 0) return;
    const int nch = (cnt + T - 1) / T;

    const int tid = threadIdx.x;
    const int wv = tid >> 6, ln = tid & 63;
    const int fr = ln & 15, fg = ln >> 4;
    const int aH = wv >> 1, tw = wv & 1;

    f32x4 kvacc[2] = {{0.f,0.f,0.f,0.f},{0.f,0.f,0.f,0.f}};
    f32x4 sacc = {0.f, 0.f, 0.f, 0.f};
    bf16x8 ones;
#pragma unroll
    for (int u = 0; u < 8; ++u) ones[u] = (short)0x3F80;

    // ============ PASS 1: {stage-transpose | KV+s} per chunk ============
    for (int c0 = 0; c0 < nch; ++c0) {
        const int t0 = c0 * T;
        const int tc = (cnt - t0 < T) ? (cnt - t0) : T;

#pragma unroll
        for (int it = 0; it < 2; ++it) {
            const int i = tid + it * BLK;
            const int t = i >> 4, c8 = (i & 15) << 3;
            bf16x8 k8, v8;
#pragma unroll
            for (int u = 0; u < 8; ++u) { k8[u] = 0; v8[u] = 0; }
            if (t < tc) {
                k8 = *(const bf16x8*)(kws + (size_t)(beg + t0 + t) * C + c8);
                v8 = *(const bf16x8*)(vws + (size_t)(beg + t0 + t) * C + c8);
            }
#pragma unroll
            for (int u = 0; u < 8; ++u) {
                const int c = c8 + u;
                const int tt = t ^ (((c >> 3) & 7) << 3);
                kT[c * KTSTR + tt] = k8[u];
                vT[c * KTSTR + tt] = v8[u];
            }
        }
        __syncthreads();

        {   // KV: kv[aH][c][d] += kT^T v (K=64); s via ones-column MFMA
#pragma unroll
            for (int kt = 0; kt < 2; ++kt) {
                const int t8 = kt * 32 + fg * 8;
                const int cch = aH * 32 + tw * 16 + fr;
                const bf16x8 a8 = *(const bf16x8*)(kT + cch * KTSTR + (t8 ^ (((cch >> 3) & 7) << 3)));
                sacc = __builtin_amdgcn_mfma_f32_16x16x32_bf16(a8, ones, sacc, 0, 0, 0);
#pragma unroll
                for (int dt = 0; dt < 2; ++dt) {
                    const int dch = aH * 32 + dt * 16 + fr;
                    const bf16x8 b8 = *(const bf16x8*)(vT + dch * KTSTR + (t8 ^ (((dch >> 3) & 7) << 3)));
                    kvacc[dt] = __builtin_amdgcn_mfma_f32_16x16x32_bf16(a8, b8, kvacc[dt], 0, 0, 0);
                }
            }
        }
        if (c0 + 1 < nch) __syncthreads();
    }

    // KV epilogue: -> kvs[h][d][c] bf16; s -> ss
    {
#pragma unroll
        for (int dt = 0; dt < 2; ++dt) {
            const int d = dt * 16 + fr;
#pragma unroll
            for (int e = 0; e < 4; ++e) {
                const int c = tw * 16 + fg * 4 + e;
                kvs[aH * (32 * KVSTR) + d * KVSTR + c] = bf16rne(kvacc[dt][e]);
            }
        }
        if (fr == 0) {
#pragma unroll
            for (int e = 0; e < 4; ++e)
                ss[aH * 32 + tw * 16 + fg * 4 + e] = sacc[e];
        }
    }
    __syncthreads();

    // ============ PASS 2: {Y (q from global, z in-wave) | PROJ} ============
    for (int c0 = 0; c0 < nch; ++c0) {
        const int t0 = c0 * T;
        const int tc = (cnt - t0 < T) ? (cnt - t0) : T;

        {   // Y: wave (a = wv>>1 head, mp = wv&1 t-half)
            const int a = wv >> 1, mp = wv & 1;
            bf16x8 bfr[2];
#pragma unroll
            for (int dl = 0; dl < 2; ++dl)
                bfr[dl] = *(const bf16x8*)(kvs + a * (32 * KVSTR) + (dl * 16 + fr) * KVSTR + fg * 8);

            const float4 s0 = *(const float4*)(ss + a * 32 + fg * 8);
            const float4 s1 = *(const float4*)(ss + a * 32 + fg * 8 + 4);

            bf16x8 afr[2];
            float zinv[2];
#pragma unroll
            for (int mi = 0; mi < 2; ++mi) {
                const int row = (mp * 2 + mi) * 16 + fr;
                afr[mi] = *(const bf16x8*)(qws + (size_t)(beg + t0 + row) * C + a * 32 + fg * 8);
                float zp = 0.f;
                zp = fmaf(bf16f(afr[mi][0]), s0.x, zp);
                zp = fmaf(bf16f(afr[mi][1]), s0.y, zp);
                zp = fmaf(bf16f(afr[mi][2]), s0.z, zp);
                zp = fmaf(bf16f(afr[mi][3]), s0.w, zp);
                zp = fmaf(bf16f(afr[mi][4]), s1.x, zp);
                zp = fmaf(bf16f(afr[mi][5]), s1.y, zp);
                zp = fmaf(bf16f(afr[mi][6]), s1.z, zp);
                zp = fmaf(bf16f(afr[mi][7]), s1.w, zp);
                zp += __shfl_xor(zp, 16);
                zp += __shfl_xor(zp, 32);
                zinv[mi] = 1.f / (zp + 1e-6f);
            }
            f32x4 acc[2][2];
#pragma unroll
            for (int mi = 0; mi < 2; ++mi)
#pragma unroll
                for (int dl = 0; dl < 2; ++dl) {
                    acc[mi][dl] = f32x4{0.f, 0.f, 0.f, 0.f};
                    acc[mi][dl] = __builtin_amdgcn_mfma_f32_16x16x32_bf16(afr[mi], bfr[dl], acc[mi][dl], 0, 0, 0);
                }
#pragma unroll
            for (int mi = 0; mi < 2; ++mi)
#pragma unroll
                for (int e = 0; e < 4; ++e) {
                    const float zt = __shfl(zinv[mi], fg * 4 + e);
                    const int t = (mp * 2 + mi) * 16 + fg * 4 + e;
#pragma unroll
                    for (int dl = 0; dl < 2; ++dl) {
                        const int ch = a * 32 + dl * 16 + fr;
                        yn[t * YNSTR + ch] = bf16rne(acc[mi][dl][e] * zt);
                    }
                }
        }
        __syncthreads();

        {   // PROJ: wave -> ntile wv
            f32x4 acc[4];
#pragma unroll
            for (int m = 0; m < 4; ++m) acc[m] = f32x4{0.f, 0.f, 0.f, 0.f};
#pragma unroll
            for (int ksi = 0; ksi < 4; ++ksi) {
                const int koff = ksi * 32 + fg * 8;
                bf16x8 a8[4];
#pragma unroll
                for (int m = 0; m < 4; ++m) {
                    const int row = m * 16 + fr;
                    a8[m] = *(const bf16x8*)(yn + row * YNSTR + koff);
                }
                const int idx = (384 + wv * 16 + fr) * C + koff;
                const bf16x8 bhi = *(const bf16x8*)(wsp + idx);
                const bf16x8 blo = *(const bf16x8*)(wsp + 65536 + idx);
#pragma unroll
                for (int m = 0; m < 4; ++m) {
                    acc[m] = __builtin_amdgcn_mfma_f32_16x16x32_bf16(a8[m], bhi, acc[m], 0, 0, 0);
                    acc[m] = __builtin_amdgcn_mfma_f32_16x16x32_bf16(a8[m], blo, acc[m], 0, 0, 0);
                }
            }
            const int ch = wv * 16 + fr;
            const float b = bproj[ch];
#pragma unroll
            for (int m = 0; m < 4; ++m)
#pragma unroll
                for (int e = 0; e < 4; ++e) {
                    const int t = m * 16 + fg * 4 + e;
                    if (t < tc)
                        out[(size_t)(beg + t0 + t) * C + ch] = acc[m][e] + b;
                }
        }
        if (c0 + 1 < nch) __syncthreads();
    }
}

// ============================================================================
// sla6 fallback (round-8 kernel) for 17MB <= ws < 50.6MB
// ============================================================================
__global__ __launch_bounds__(BLK, 2)
void sla6(const float* __restrict__ x, const float* __restrict__ bproj,
          const int* __restrict__ offsets, const short* __restrict__ wsp,
          short* __restrict__ qws, float* __restrict__ out)
{
    __shared__ __align__(16) short xs_hi[T * C];
    __shared__ __align__(16) short xs_lo[T * C];
    __shared__ __align__(16) short kT[C * T];
    __shared__ __align__(16) short vTy[C * T];
    __shared__ __align__(16) short kvs[4 * 32 * KVSTR];
    __shared__ float ss[C];

    const int win = blockIdx.x;
    const int beg = offsets[win];
    const int cnt = offsets[win + 1] - beg;
    if (cnt <= 0) return;
    const int nch = (cnt + T - 1) / T;

    const int tid = threadIdx.x;
    const int wv = tid >> 6, ln = tid & 63;
    const int fr = ln & 15, fg = ln >> 4;

    auto loadB = [&](int row512, int koff, bf16x8& bhi, bf16x8& blo) {
        const int idx = row512 * C + koff;
        bhi = *(const bf16x8*)(wsp + idx);
        blo = *(const bf16x8*)(wsp + 65536 + idx);
    };
    auto stage = [&](int t0, int tc) {
#pragma unroll
        for (int it = 0; it < 2; ++it) {
            const int i = tid + it * BLK;
            const int t = i >> 4, c8 = (i & 15) << 3;
            float4 a = {0.f, 0.f, 0.f, 0.f}, b = {0.f, 0.f, 0.f, 0.f};
            if (t < tc) {
                const float* p = x + (size_t)(beg + t0 + t) * C + c8;
                a = *(const float4*)p;
                b = *(const float4*)(p + 4);
            }
            const float f[8] = {a.x, a.y, a.z, a.w, b.x, b.y, b.z, b.w};
            bf16x8 hi, lo;
#pragma unroll
            for (int u = 0; u < 8; ++u) { short h_, l_; split1(f[u], h_, l_); hi[u] = h_; lo[u] = l_; }
            const int s = t * C + (c8 ^ ((t & 7) << 3));
            *(bf16x8*)(xs_hi + s) = hi;
            *(bf16x8*)(xs_lo + s) = lo;
        }
    };

    const int aH = wv >> 1, tw = wv & 1;
    f32x4 kvacc[2] = {{0.f,0.f,0.f,0.f},{0.f,0.f,0.f,0.f}};
    f32x4 sacc = {0.f, 0.f, 0.f, 0.f};
    bf16x8 ones;
#pragma unroll
    for (int u = 0; u < 8; ++u) ones[u] = (short)0x3F80;

    for (int c0 = 0; c0 < nch; ++c0) {
        const int t0 = c0 * T;
        const int tc = (cnt - t0 < T) ? (cnt - t0) : T;
        stage(t0, tc);
        __syncthreads();
        sh4 qreg[4];
        {
            f32x4 acc[2][4];
#pragma unroll
            for (int ni = 0; ni < 2; ++ni)
#pragma unroll
                for (int m = 0; m < 4; ++m) acc[ni][m] = f32x4{0.f, 0.f, 0.f, 0.f};
#pragma unroll
            for (int ksi = 0; ksi < 4; ++ksi) {
                const int koff = ksi * 32 + fg * 8;
                bf16x8 ahi[4], alo[4];
#pragma unroll
                for (int m = 0; m < 4; ++m) {
                    const int row = m * 16 + fr;
                    const int s = row * C + (koff ^ ((row & 7) << 3));
                    ahi[m] = *(const bf16x8*)(xs_hi + s);
                    alo[m] = *(const bf16x8*)(xs_lo + s);
                }
#pragma unroll
                for (int ni = 0; ni < 2; ++ni) {
                    bf16x8 bhi, blo;
                    loadB(128 + (2 * wv + ni) * 16 + fr, koff, bhi, blo);
#pragma unroll
                    for (int m = 0; m < 4; ++m) {
                        acc[ni][m] = __builtin_amdgcn_mfma_f32_16x16x32_bf16(ahi[m], bhi, acc[ni][m], 0, 0, 0);
                        acc[ni][m] = __builtin_amdgcn_mfma_f32_16x16x32_bf16(ahi[m], blo, acc[ni][m], 0, 0, 0);
                        acc[ni][m] = __builtin_amdgcn_mfma_f32_16x16x32_bf16(alo[m], bhi, acc[ni][m], 0, 0, 0);
                    }
                }
            }
#pragma unroll
            for (int ni = 0; ni < 2; ++ni) {
                const int nt = 2 * wv + ni;
                const bool isk = (nt < 8);
                const int ch = (isk ? nt : nt - 8) * 16 + fr;
                short* dst = isk ? kT : vTy;
#pragma unroll
                for (int m = 0; m < 4; ++m) {
                    sh4 h4;
#pragma unroll
                    for (int e = 0; e < 4; ++e) {
                        float v = acc[ni][m][e];
                        if (isk) v = fmaxf(v, 0.f);
                        h4[e] = bf16rne(v);
                    }
                    const int tb = m * 16 + fg * 4;
                    *(sh4*)(dst + ch * T + (tb ^ ((ch & 7) << 3))) = h4;
                }
            }
        }
        {
            f32x4 acc[4];
#pragma unroll
            for (int m = 0; m < 4; ++m) acc[m] = f32x4{0.f, 0.f, 0.f, 0.f};
#pragma unroll
            for (int ksi = 0; ksi < 4; ++ksi) {
                const int koff = ksi * 32 + fg * 8;
                bf16x8 ahi[4], alo[4];
#pragma unroll
                for (int m = 0; m < 4; ++m) {
                    const int row = m * 16 + fr;
                    const int s = row * C + (koff ^ ((row & 7) << 3));
                    ahi[m] = *(const bf16x8*)(xs_hi + s);
                    alo[m] = *(const bf16x8*)(xs_lo + s);
                }
                bf16x8 bhi, blo;
                loadB(wv * 16 + fr, koff, bhi, blo);
#pragma unroll
                for (int m = 0; m < 4; ++m) {
                    acc[m] = __builtin_amdgcn_mfma_f32_16x16x32_bf16(ahi[m], bhi, acc[m], 0, 0, 0);
                    acc[m] = __builtin_amdgcn_mfma_f32_16x16x32_bf16(ahi[m], blo, acc[m], 0, 0, 0);
                    acc[m] = __builtin_amdgcn_mfma_f32_16x16x32_bf16(alo[m], bhi, acc[m], 0, 0, 0);
                }
            }
#pragma unroll
            for (int m = 0; m < 4; ++m)
#pragma unroll
                for (int e = 0; e < 4; ++e)
                    qreg[m][e] = bf16rne(fmaxf(acc[m][e], 0.f));
        }
        __syncthreads();
        {
            const int ch = wv * 16 + fr;
            if (nch == 1) {
#pragma unroll
                for (int m = 0; m < 4; ++m)
#pragma unroll
                    for (int e = 0; e < 4; ++e) {
                        const int t = m * 16 + fg * 4 + e;
                        xs_hi[t * C + (ch ^ ((t & 7) << 3))] = qreg[m][e];
                    }
            } else {
#pragma unroll
                for (int m = 0; m < 4; ++m)
#pragma unroll
                    for (int e = 0; e < 4; ++e) {
                        const int t = m * 16 + fg * 4 + e;
                        if (t < tc)
                            qws[(size_t)(beg + t0 + t) * C + ch] = qreg[m][e];
                    }
            }
        }
        {
#pragma unroll
            for (int kt = 0; kt < 2; ++kt) {
                const int t8 = kt * 32 + fg * 8;
                const int cch = aH * 32 + tw * 16 + fr;
                const bf16x8 a8 = *(const bf16x8*)(kT + cch * T + (t8 ^ ((cch & 7) << 3)));
                sacc = __builtin_amdgcn_mfma_f32_16x16x32_bf16(a8, ones, sacc, 0, 0, 0);
#pragma unroll
                for (int dt = 0; dt < 2; ++dt) {
                    const int dch = aH * 32 + dt * 16 + fr;
                    const bf16x8 b8 = *(const bf16x8*)(vTy + dch * T + (t8 ^ ((dch & 7) << 3)));
                    kvacc[dt] = __builtin_amdgcn_mfma_f32_16x16x32_bf16(a8, b8, kvacc[dt], 0, 0, 0);
                }
            }
        }
        if (c0 + 1 < nch) __syncthreads();
    }
    {
#pragma unroll
        for (int dt = 0; dt < 2; ++dt) {
            const int d = dt * 16 + fr;
#pragma unroll
            for (int e = 0; e < 4; ++e) {
                const int c = tw * 16 + fg * 4 + e;
                kvs[aH * (32 * KVSTR) + d * KVSTR + c] = bf16rne(kvacc[dt][e]);
            }
        }
        if (fr == 0) {
#pragma unroll
            for (int e = 0; e < 4; ++e)
                ss[aH * 32 + tw * 16 + fg * 4 + e] = sacc[e];
        }
    }
    __syncthreads();
    for (int c0 = 0; c0 < nch; ++c0) {
        const int t0 = c0 * T;
        const int tc = (cnt - t0 < T) ? (cnt - t0) : T;
        {
            const int a = wv >> 1, mp = wv & 1;
            bf16x8 bfr[2];
#pragma unroll
            for (int dl = 0; dl < 2; ++dl)
                bfr[dl] = *(const bf16x8*)(kvs + a * (32 * KVSTR) + (dl * 16 + fr) * KVSTR + fg * 8);
            const float4 s0 = *(const float4*)(ss + a * 32 + fg * 8);
            const float4 s1 = *(const float4*)(ss + a * 32 + fg * 8 + 4);
            bf16x8 afr[2];
            float zinv[2];
#pragma unroll
            for (int mi = 0; mi < 2; ++mi) {
                const int row = (mp * 2 + mi) * 16 + fr;
                if (nch == 1)
                    afr[mi] = *(const bf16x8*)(xs_hi + row * C + ((a * 32 + fg * 8) ^ ((row & 7) << 3)));
                else
                    afr[mi] = *(const bf16x8*)(qws + (size_t)(beg + t0 + row) * C + a * 32 + fg * 8);
                float zp = 0.f;
                zp = fmaf(bf16f(afr[mi][0]), s0.x, zp);
                zp = fmaf(bf16f(afr[mi][1]), s0.y, zp);
                zp = fmaf(bf16f(afr[mi][2]), s0.z, zp);
                zp = fmaf(bf16f(afr[mi][3]), s0.w, zp);
                zp = fmaf(bf16f(afr[mi][4]), s1.x, zp);
                zp = fmaf(bf16f(afr[mi][5]), s1.y, zp);
                zp = fmaf(bf16f(afr[mi][6]), s1.z, zp);
                zp = fmaf(bf16f(afr[mi][7]), s1.w, zp);
                zp += __shfl_xor(zp, 16);
                zp += __shfl_xor(zp, 32);
                zinv[mi] = 1.f / (zp + 1e-6f);
            }
            f32x4 acc[2][2];
#pragma unroll
            for (int mi = 0; mi < 2; ++mi)
#pragma unroll
                for (int dl = 0; dl < 2; ++dl) {
                    acc[mi][dl] = f32x4{0.f, 0.f, 0.f, 0.f};
                    acc[mi][dl] = __builtin_amdgcn_mfma_f32_16x16x32_bf16(afr[mi], bfr[dl], acc[mi][dl], 0, 0, 0);
                }
#pragma unroll
            for (int mi = 0; mi < 2; ++mi)
#pragma unroll
                for (int e = 0; e < 4; ++e) {
                    const float zt = __shfl(zinv[mi], fg * 4 + e);
                    const int t = (mp * 2 + mi) * 16 + fg * 4 + e;
#pragma unroll
                    for (int dl = 0; dl < 2; ++dl) {
                        const int ch = a * 32 + dl * 16 + fr;
                        vTy[t * C + (ch ^ ((t & 7) << 3))] = bf16rne(acc[mi][dl][e] * zt);
                    }
                }
        }
        __syncthreads();
        {
            f32x4 acc[4];
#pragma unroll
            for (int m = 0; m < 4; ++m) acc[m] = f32x4{0.f, 0.f, 0.f, 0.f};
#pragma unroll
            for (int ksi = 0; ksi < 4; ++ksi) {
                const int koff = ksi * 32 + fg * 8;
                bf16x8 a8[4];
#pragma unroll
                for (int m = 0; m < 4; ++m) {
                    const int row = m * 16 + fr;
                    a8[m] = *(const bf16x8*)(vTy + row * C + (koff ^ ((row & 7) << 3)));
                }
                bf16x8 bhi, blo;
                loadB(384 + wv * 16 + fr, koff, bhi, blo);
#pragma unroll
                for (int m = 0; m < 4; ++m) {
                    acc[m] = __builtin_amdgcn_mfma_f32_16x16x32_bf16(a8[m], bhi, acc[m], 0, 0, 0);
                    acc[m] = __builtin_amdgcn_mfma_f32_16x16x32_bf16(a8[m], blo, acc[m], 0, 0, 0);
                }
            }
            const int ch = wv * 16 + fr;
            const float b = bproj[ch];
#pragma unroll
            for (int m = 0; m < 4; ++m)
#pragma unroll
                for (int e = 0; e < 4; ++e) {
                    const int t = m * 16 + fg * 4 + e;
                    if (t < tc)
                        out[(size_t)(beg + t0 + t) * C + ch] = acc[m][e] + b;
                }
        }
        if (c0 + 1 < nch) __syncthreads();
    }
}

extern "C" void kernel_launch(void* const* d_in, const int* in_sizes, int n_in,
                              void* d_out, int out_size, void* d_ws, size_t ws_size,
                              hipStream_t stream)
{
    const float* x       = (const float*)d_in[0];
    const float* wqkv    = (const float*)d_in[1];
    const float* wproj   = (const float*)d_in[2];
    const float* bproj   = (const float*)d_in[3];
    const int*   offsets = (const int*)d_in[5];
    float* out = (float*)d_out;
    short* wsp = (short*)d_ws;

    const size_t need_split = ((size_t)WSPN + 3 * QN) * sizeof(short);
    const size_t need_sla6  = ((size_t)WSPN + QN) * sizeof(short);

    if (ws_size >= need_split) {
        short* qws = wsp + WSPN;
        short* kws = qws + QN;
        short* vws = kws + QN;
        hipLaunchKernelGGL(prep_weights, dim3(256), dim3(256), 0, stream, wqkv, wproj, wsp);
        hipLaunchKernelGGL(qkv_gemm, dim3(65536 / 64), dim3(BLK), 0, stream,
                           x, wsp, qws, kws, vws);
        hipLaunchKernelGGL(sla_win, dim3(NWIN), dim3(BLK), 0, stream,
                           qws, kws, vws, wsp, bproj, offsets, out);
    } else if (ws_size >= need_sla6) {
        hipLaunchKernelGGL(prep_weights, dim3(256), dim3(256), 0, stream, wqkv, wproj, wsp);
        hipLaunchKernelGGL(sla6, dim3(NWIN), dim3(BLK), 0, stream,
                           x, bproj, offsets, wsp, wsp + WSPN, out);
    }
}